// Round 7
// baseline (1270.400 us; speedup 1.0000x reference)
//
#include <hip/hip_runtime.h>
#include <math.h>

#define BN 64
#define KIN 1024
#define DOUT 512
#define NN 2048
#define TBLK 128
#define NBLK 16

// Branchless nonlinearity: compute all candidates, select via cndmask tree.
// 0 ReLU, 1 Tanh, 2 LeakyReLU, 3 Identity, 4 Sine, 5 Softplus, 6 SoftMinus
__device__ __forceinline__ float apply_nl(int id, float v) {
  float t  = fabsf(v);
  float e  = __expf(-t);
  float l1 = __logf(1.f + e);
  float mx = fmaxf(v, 0.f);
  float sp = mx + l1;                                  // softplus
  float sm = v - sp;                                   // -softplus(-v)
  float e2 = e * e;
  float th = __builtin_copysignf((1.f - e2) * __builtin_amdgcn_rcpf(1.f + e2), v);
  float lk = mx + 0.01f * fminf(v, 0.f);               // leaky
  float sn = __sinf(v);
  float r = v;                                         // id==3
  r = (id == 0) ? mx : r;
  r = (id == 1) ? th : r;
  r = (id == 2) ? lk : r;
  r = (id == 4) ? sn : r;
  r = (id == 5) ? sp : r;
  r = (id == 6) ? sm : r;
  return r;
}

// ---------------- adj dtype detection (parallel) ----------------
__global__ void detect_adj(const unsigned int* __restrict__ a, int* __restrict__ flags) {
  int idx = blockIdx.x * 256 + threadIdx.x;  // 16384 dwords = first 64 KiB
  unsigned int v = a[idx];
  bool bad = ((v & 0xFFu) > 1u) || (((v >> 8) & 0xFFu) > 1u) ||
             (((v >> 16) & 0xFFu) > 1u) || ((v >> 24) > 1u);
  bool off = (v & 0xFFFFFF00u) != 0u;
  if (__any(bad) && (threadIdx.x & 63) == 0) atomicOr(&flags[0], 1);
  if (__any(off) && (threadIdx.x & 63) == 0) atomicOr(&flags[1], 1);
}

__global__ void normalize_adj(const unsigned char* __restrict__ a,
                              const int* __restrict__ flags,
                              unsigned char* __restrict__ out) {
  size_t i = (size_t)blockIdx.x * blockDim.x + threadIdx.x;
  int mode = flags[0] ? 2 : (flags[1] ? 1 : 0);
  unsigned char r;
  if (mode == 1)      r = (a[i] != 0);
  else if (mode == 0) r = (((const int*)a)[i] != 0);
  else                r = (((const float*)a)[i] != 0.f);
  out[i] = r;
}

// ---------------- X transpose ----------------
__global__ void transpose_x(const float* __restrict__ X, float* __restrict__ XT) {
  int g = blockIdx.x * blockDim.x + threadIdx.x;
  int k = g >> 6, b = g & 63;
  XT[g] = X[(size_t)b * KIN + k];
}

// ---------------- pack aligned in-block triangles (Phase B source) ----------------
__global__ __launch_bounds__(256) void pack_wmid(const float* __restrict__ Wmid,
                                                 const unsigned char* __restrict__ adjN,
                                                 float* __restrict__ wpack) {
  int g = blockIdx.x * 256 + threadIdx.x;  // 65536 float4s
  int i = g >> 12;
  int rem = g & 4095;
  int j = rem >> 5;
  int q4 = (rem & 31) * 4;
  int n0 = 1 + i * TBLK;
  int size = NN - 1 - n0;
  if (size > TBLK) size = TBLK;
  float w[4];
#pragma unroll
  for (int e = 0; e < 4; ++e) {
    int q = q4 + e;
    float v = 0.f;
    if (q > j && j < size && q < size) {
      size_t idx = (size_t)(n0 + j) * NN + (size_t)(n0 + q);
      v = Wmid[idx] * (float)adjN[idx];
    }
    w[e] = v;
  }
  *(float4*)(wpack + (size_t)g * 4) = make_float4(w[0], w[1], w[2], w[3]);
}

// ---------------- pack left-shifted per-chunk rows (Phase A shift-register source) ----
// lp[blk][c][jj][i] = masked W[n0+c*32+jj][n0+c*32+jj+1+i], i<=30-jj, else 0
__global__ __launch_bounds__(256) void pack_lp(const float* __restrict__ Wmid,
                                               const unsigned char* __restrict__ adjN,
                                               float* __restrict__ lppack) {
  int g = blockIdx.x * 256 + threadIdx.x;  // 65536 floats
  int blk = g >> 12;
  int r = g & 4095;
  int c = r >> 10;
  int jj = (r >> 5) & 31;
  int i = r & 31;
  int n0 = 1 + blk * TBLK;
  int size = NN - 1 - n0;
  if (size > TBLK) size = TBLK;
  int j = c * 32 + jj;          // local row
  int col = j + 1 + i;          // local col
  float v = 0.f;
  if (i <= 30 - jj && j < size && col < size) {
    size_t idx = (size_t)(n0 + j) * NN + (size_t)(n0 + col);
    v = Wmid[idx] * (float)adjN[idx];
  }
  lppack[g] = v;
}

// ---------------- unified partial GEMM ----------------
// MODE 0: no mask. MODE 1: element mask. MODE 2: row mask (adj[:,NN-1]). All atomic acc.
template <int MODE>
__global__ __launch_bounds__(256) void gemm_partial(
    const float* __restrict__ AT, const float* __restrict__ W,
    const unsigned char* __restrict__ adj, float* __restrict__ accT,
    int ldw, int col0, int ncols, int kPerChunk, int nColTiles)
{
  const int ct = blockIdx.x % nColTiles;
  const int kc = blockIdx.x / nColTiles;
  const int c0 = ct * 64;
  const int k0 = kc * kPerChunk;
  const int t = threadIdx.x;
  const int tb = t >> 4;
  const int tc = t & 15;

  __shared__ __align__(16) float At[16][64];
  __shared__ __align__(16) float Wt[16][64];

  float acc[4][4] = {};
  const int sk = t >> 4;
  const int sq = t & 15;

  for (int ks = k0; ks < k0 + kPerChunk; ks += 16) {
    const float4 av = *(const float4*)(AT + (size_t)(ks + sk) * 64 + sq * 4);
    *(float4*)(&At[sk][sq * 4]) = av;
    {
      const float* wrow = W + (size_t)(ks + sk) * ldw + col0;
      float w[4];
      float rowmask = 1.f;
      if (MODE == 2) rowmask = (float)adj[(size_t)(ks + sk) * NN + (NN - 1)];
#pragma unroll
      for (int e = 0; e < 4; ++e) {
        int cl = c0 + sq * 4 + e;
        float wv = 0.f;
        if (cl < ncols) {
          wv = wrow[cl];
          if (MODE == 1) wv *= (float)adj[(size_t)(ks + sk) * NN + col0 + cl];
          if (MODE == 2) wv *= rowmask;
        }
        w[e] = wv;
      }
      *(float4*)(&Wt[sk][sq * 4]) = make_float4(w[0], w[1], w[2], w[3]);
    }
    __syncthreads();
#pragma unroll
    for (int kk = 0; kk < 16; ++kk) {
      float a4[4], w4[4];
#pragma unroll
      for (int e = 0; e < 4; ++e) a4[e] = At[kk][tb * 4 + e];
#pragma unroll
      for (int e = 0; e < 4; ++e) w4[e] = Wt[kk][tc * 4 + e];
#pragma unroll
      for (int i = 0; i < 4; ++i)
#pragma unroll
        for (int j = 0; j < 4; ++j) acc[i][j] = fmaf(a4[i], w4[j], acc[i][j]);
    }
    __syncthreads();
  }

#pragma unroll
  for (int j = 0; j < 4; ++j) {
    int cl = c0 + tc * 4 + j;
    if (cl < ncols) {
      float* dst = accT + (size_t)(col0 + cl) * 64 + tb * 4;
#pragma unroll
      for (int i = 0; i < 4; ++i) atomicAdd(dst + i, acc[i][j]);
    }
  }
}

// ---------------- init finish ----------------
__global__ void init_finish(const float* __restrict__ out0accT, const float* __restrict__ b0,
                            const unsigned char* __restrict__ adjN, const int* __restrict__ nl_idx,
                            float* __restrict__ curT) {
  int g = blockIdx.x * blockDim.x + threadIdx.x;
  int n = g >> 6;
  float v = out0accT[g] + b0[n];
  v = apply_nl(nl_idx[0], v);
  curT[g] = adjN[n] ? v : 0.f;
}

// ---------------- sequential in-block solver: rolled loops + shift-register Phase A --
__global__ __launch_bounds__(256, 1) void seq_block(
    const float* __restrict__ wpack, const float* __restrict__ lppack,
    const int* __restrict__ nlidx, const float* __restrict__ bmid,
    const float* __restrict__ CaccT, float* __restrict__ curT,
    float* __restrict__ deltaG, int blk, int n0, int size)
{
  __shared__ __align__(16) float wmS[TBLK][TBLK];       // 64 KiB aligned triangle (B)
  __shared__ __align__(16) float lpS[4][32][32];        // 16 KiB left-packed rows (A)
  __shared__ __align__(16) float ivS[TBLK][64];         // 32 KiB init values
  __shared__ __align__(16) float deltaFull[TBLK][64];   // 32 KiB deltas
  __shared__ int idS[TBLK];                             // 512 B
  const int tid = threadIdx.x;
  const int wv = tid >> 6;
  const int b = tid & 63;
  const int qbase = wv * 32;

  // ---- issue all staging loads into registers (latency overlapped) ----
  const float4* src = (const float4*)(wpack + (size_t)blk * TBLK * TBLK);
  float4 stg[16];
#pragma unroll
  for (int it = 0; it < 16; ++it) stg[it] = src[it * 256 + tid];
  const float4* lsrc = (const float4*)(lppack + (size_t)blk * 4096);
  float4 lstg[4];
#pragma unroll
  for (int it = 0; it < 4; ++it) lstg[it] = lsrc[it * 256 + tid];
  const float4* ivsrc = (const float4*)(curT + (size_t)n0 * 64);
  float4 ivstg[8];
#pragma unroll
  for (int it = 0; it < 8; ++it) ivstg[it] = ivsrc[it * 256 + tid];

  // ---- val preload (registers, static indices) ----
  float val[33];
#pragma unroll
  for (int l = 0; l < 32; ++l) {
    int q = qbase + l;
    int n = n0 + q;
    val[l] = (q < size) ? (CaccT[(size_t)n * 64 + b] + bmid[n]) : 0.f;
  }
  val[32] = 0.f;
  if (tid < TBLK) idS[tid] = (tid < size) ? nlidx[n0 + tid] : 3;

  // ---- commit staged data to LDS ----
#pragma unroll
  for (int it = 0; it < 16; ++it) ((float4*)&wmS[0][0])[it * 256 + tid] = stg[it];
#pragma unroll
  for (int it = 0; it < 4; ++it) ((float4*)&lpS[0][0][0])[it * 256 + tid] = lstg[it];
#pragma unroll
  for (int it = 0; it < 8; ++it) ((float4*)&ivS[0][0])[it * 256 + tid] = ivstg[it];
  __syncthreads();

#pragma unroll 1
  for (int c = 0; c < 4; ++c) {
    if (wv == c) {
      // ---- Phase A: rolled 32-step shift-register solve of own chunk ----
      const int jbase = c * 32;
      const float4* lpr = (const float4*)&lpS[c][0][0];
      float4 wrow[8];
#pragma unroll
      for (int g = 0; g < 8; ++g) wrow[g] = lpr[g];
      float ivv = ivS[jbase][b];
      int idv = idS[jbase];
#pragma unroll 1
      for (int jj = 0; jj < 32; ++jj) {
        const int j = jbase + jj;
        float nv = apply_nl(idv, val[0]);
        float delta = nv - ivv;
        if (j < size) {
          curT[(size_t)(n0 + j) * 64 + b] = nv;  // fire-and-forget
        } else {
          delta = 0.f;
        }
        deltaFull[j][b] = delta;
        // prefetch next row + next iv/id (consumed next iteration)
        const int pj = (jj < 31) ? jj + 1 : jj;
        float4 wnxt[8];
#pragma unroll
        for (int g = 0; g < 8; ++g) wnxt[g] = lpr[pj * 8 + g];
        ivv = ivS[jbase + pj][b];
        idv = idS[jbase + pj];
        // shift-register fma: val[i] = delta*w[i] + val[i+1]
#pragma unroll
        for (int g = 0; g < 8; ++g) {
          val[g * 4 + 0] = fmaf(delta, wrow[g].x, val[g * 4 + 1]);
          val[g * 4 + 1] = fmaf(delta, wrow[g].y, val[g * 4 + 2]);
          val[g * 4 + 2] = fmaf(delta, wrow[g].z, val[g * 4 + 3]);
          val[g * 4 + 3] = fmaf(delta, wrow[g].w, val[g * 4 + 4]);
        }
#pragma unroll
        for (int g = 0; g < 8; ++g) wrow[g] = wnxt[g];
      }
#pragma unroll
      for (int l = 0; l < 33; ++l) val[l] = 0.f;  // chunk consumed
    }
    __syncthreads();  // deltas visible
    if (wv > c) {
      // ---- Phase B: rolled rank-32 update of own (not yet solved) slots ----
#pragma unroll 1
      for (int jj = 0; jj < 32; ++jj) {
        const int j = c * 32 + jj;
        const float delta = deltaFull[j][b];
        const float4* wr = (const float4*)(&wmS[j][qbase]);
        float4 w0 = wr[0], w1 = wr[1], w2 = wr[2], w3 = wr[3];
        float4 w4 = wr[4], w5 = wr[5], w6 = wr[6], w7 = wr[7];
        val[0] = fmaf(delta, w0.x, val[0]);   val[1] = fmaf(delta, w0.y, val[1]);
        val[2] = fmaf(delta, w0.z, val[2]);   val[3] = fmaf(delta, w0.w, val[3]);
        val[4] = fmaf(delta, w1.x, val[4]);   val[5] = fmaf(delta, w1.y, val[5]);
        val[6] = fmaf(delta, w1.z, val[6]);   val[7] = fmaf(delta, w1.w, val[7]);
        val[8] = fmaf(delta, w2.x, val[8]);   val[9] = fmaf(delta, w2.y, val[9]);
        val[10] = fmaf(delta, w2.z, val[10]); val[11] = fmaf(delta, w2.w, val[11]);
        val[12] = fmaf(delta, w3.x, val[12]); val[13] = fmaf(delta, w3.y, val[13]);
        val[14] = fmaf(delta, w3.z, val[14]); val[15] = fmaf(delta, w3.w, val[15]);
        val[16] = fmaf(delta, w4.x, val[16]); val[17] = fmaf(delta, w4.y, val[17]);
        val[18] = fmaf(delta, w4.z, val[18]); val[19] = fmaf(delta, w4.w, val[19]);
        val[20] = fmaf(delta, w5.x, val[20]); val[21] = fmaf(delta, w5.y, val[21]);
        val[22] = fmaf(delta, w5.z, val[22]); val[23] = fmaf(delta, w5.w, val[23]);
        val[24] = fmaf(delta, w6.x, val[24]); val[25] = fmaf(delta, w6.y, val[25]);
        val[26] = fmaf(delta, w6.z, val[26]); val[27] = fmaf(delta, w6.w, val[27]);
        val[28] = fmaf(delta, w7.x, val[28]); val[29] = fmaf(delta, w7.y, val[29]);
        val[30] = fmaf(delta, w7.z, val[30]); val[31] = fmaf(delta, w7.w, val[31]);
      }
    }
    __syncthreads();
  }

  // ---- export deltas: coalesced copy (off the serial path) ----
  {
    float4* dst = (float4*)(deltaG + (size_t)blk * TBLK * 64);
    const float4* sdel = (const float4*)&deltaFull[0][0];
#pragma unroll
    for (int it = 0; it < 8; ++it) dst[it * 256 + tid] = sdel[it * 256 + tid];
  }
}

// ---------------- final finish ----------------
__global__ void final_finish(const float* __restrict__ outaccT, const float* __restrict__ bout,
                             const int* __restrict__ nlidx, float* __restrict__ out) {
  int g = blockIdx.x * blockDim.x + threadIdx.x;
  int c = g >> 6, b = g & 63;
  float v = outaccT[g] + bout[c];
  v = apply_nl(nlidx[NN - 1], v);
  out[(size_t)b * DOUT + c] = v;
}

// ---------------- state transpose ----------------
__global__ __launch_bounds__(256) void transpose_state(const float* __restrict__ curT,
                                                       float* __restrict__ stateOut) {
  __shared__ float tile[64][65];
  int n0 = blockIdx.x * 64;
  for (int r = 0; r < 16; ++r) {
    int e = r * 256 + threadIdx.x;
    tile[e >> 6][e & 63] = curT[(size_t)(n0 + (e >> 6)) * 64 + (e & 63)];
  }
  __syncthreads();
  for (int r = 0; r < 16; ++r) {
    int e = r * 256 + threadIdx.x;
    int bb = e >> 6, nn2 = e & 63;
    stateOut[(size_t)bb * NN + n0 + nn2] = tile[nn2][bb];
  }
}

extern "C" void kernel_launch(void* const* d_in, const int* in_sizes, int n_in,
                              void* d_out, int out_size, void* d_ws, size_t ws_size,
                              hipStream_t stream) {
  const float* X = (const float*)d_in[0];
  const unsigned char* adj = (const unsigned char*)d_in[1];
  const int* nl_idx = (const int*)d_in[2];
  const float* W0 = (const float*)d_in[3];
  const float* b0 = (const float*)d_in[4];
  const float* W_mid = (const float*)d_in[5];
  const float* b_mid = (const float*)d_in[6];
  const float* W_out = (const float*)d_in[7];
  const float* b_out = (const float*)d_in[8];
  float* out = (float*)d_out;
  float* stateOut = out + BN * DOUT;

  char* ws = (char*)d_ws;
  unsigned char* adjN = (unsigned char*)(ws + 0);       // 4 MiB
  int* flags = (int*)(ws + 4194304);                    // 256 B
  float* XT = (float*)(ws + 4194560);                   // 256 KiB
  float* curT = (float*)(ws + 4456704);                 // 512 KiB
  float* CbaseT = (float*)(ws + 4980992);               // 512 KiB (zeroed acc, updated in place)
  float* out0accT = (float*)(ws + 5505280);             // 512 KiB (zeroed acc)
  float* outaccT = (float*)(ws + 6029568);              // 128 KiB (zeroed acc)
  float* wpack = (float*)(ws + 6160640);                // 1 MiB
  float* deltaG = (float*)(ws + 7209216);               // 512 KiB
  float* lppack = (float*)(ws + 7733504);               // 256 KiB -> end 7995648

  hipMemsetAsync(flags, 0, 256, stream);
  hipMemsetAsync(CbaseT, 0, 524288 + 524288 + 131072, stream);

  detect_adj<<<64, 256, 0, stream>>>((const unsigned int*)adj, flags);
  normalize_adj<<<16384, 256, 0, stream>>>(adj, flags, adjN);
  transpose_x<<<256, 256, 0, stream>>>(X, XT);
  pack_wmid<<<256, 256, 0, stream>>>(W_mid, adjN, wpack);
  pack_lp<<<256, 256, 0, stream>>>(W_mid, adjN, lppack);

  // node 0: out0accT = X @ W0
  gemm_partial<0><<<128, 256, 0, stream>>>(XT, W0, adjN, out0accT, NN, 0, NN, 256, 32);
  init_finish<<<512, 256, 0, stream>>>(out0accT, b0, adjN, nl_idx, curT);

  // Cbase: state_0 @ (W_mid * adj) for ALL columns (one big parallel GEMM)
  gemm_partial<1><<<256, 256, 0, stream>>>(curT, W_mid, adjN, CbaseT, NN, 0, NN, 256, 32);

  // sequential middle: solve block j, then rank-128 update of all later columns
  for (int j = 0; j < NBLK; ++j) {
    int n0 = 1 + j * TBLK;
    int size = NN - 1 - n0;
    if (size > TBLK) size = TBLK;
    seq_block<<<1, 256, 0, stream>>>(wpack, lppack, nl_idx, b_mid, CbaseT, curT,
                                     deltaG, j, n0, size);
    if (j < NBLK - 1) {
      int rowbase = n0;                 // 128 rows of block j
      int col0 = 1 + (j + 1) * TBLK;    // first column of block j+1
      int ncols = (NN - 1) - col0;      // middle cols only (n <= 2046)
      int tiles = (ncols + 63) / 64;
      gemm_partial<1><<<tiles * 2, 256, 0, stream>>>(
          deltaG + (size_t)j * TBLK * 64, W_mid + (size_t)rowbase * NN,
          adjN + (size_t)rowbase * NN, CbaseT, NN, col0, ncols, 64, tiles);
    }
  }

  gemm_partial<2><<<64, 256, 0, stream>>>(curT, W_out, adjN, outaccT, DOUT, 0, DOUT, 256, 8);
  final_finish<<<128, 256, 0, stream>>>(outaccT, b_out, nl_idx, out);
  transpose_state<<<32, 256, 0, stream>>>(curT, stateOut);
}

// Round 8
// 1144.090 us; speedup vs baseline: 1.1104x; 1.1104x over previous
//
#include <hip/hip_runtime.h>
#include <math.h>

#define BN 64
#define KIN 1024
#define DOUT 512
#define NN 2048
#define TBLK 128
#define NBLK 16

__device__ __forceinline__ float softplus_f(float x) {
  float e = __expf(-fabsf(x));
  return fmaxf(x, 0.f) + __logf(1.f + e);
}
__device__ __forceinline__ float apply_nl(int id, float v) {
  switch (id) {
    case 0: return fmaxf(v, 0.f);
    case 1: { float e = __expf(2.f * v); return fmaf(-2.f, __builtin_amdgcn_rcpf(e + 1.f), 1.f); }
    case 2: return v >= 0.f ? v : 0.01f * v;
    case 3: return v;
    case 4: return __sinf(v);
    case 5: return softplus_f(v);
    default: return v - softplus_f(v);  // -softplus(-v)
  }
}

// ---------------- adj dtype detection (parallel) ----------------
__global__ void detect_adj(const unsigned int* __restrict__ a, int* __restrict__ flags) {
  int idx = blockIdx.x * 256 + threadIdx.x;  // 16384 dwords = first 64 KiB
  unsigned int v = a[idx];
  bool bad = ((v & 0xFFu) > 1u) || (((v >> 8) & 0xFFu) > 1u) ||
             (((v >> 16) & 0xFFu) > 1u) || ((v >> 24) > 1u);
  bool off = (v & 0xFFFFFF00u) != 0u;
  if (__any(bad) && (threadIdx.x & 63) == 0) atomicOr(&flags[0], 1);
  if (__any(off) && (threadIdx.x & 63) == 0) atomicOr(&flags[1], 1);
}

__global__ void normalize_adj(const unsigned char* __restrict__ a,
                              const int* __restrict__ flags,
                              unsigned char* __restrict__ out) {
  size_t i = (size_t)blockIdx.x * blockDim.x + threadIdx.x;
  int mode = flags[0] ? 2 : (flags[1] ? 1 : 0);
  unsigned char r;
  if (mode == 1)      r = (a[i] != 0);
  else if (mode == 0) r = (((const int*)a)[i] != 0);
  else                r = (((const float*)a)[i] != 0.f);
  out[i] = r;
}

// ---------------- X transpose ----------------
__global__ void transpose_x(const float* __restrict__ X, float* __restrict__ XT) {
  int g = blockIdx.x * blockDim.x + threadIdx.x;
  int k = g >> 6, b = g & 63;
  XT[g] = X[(size_t)b * KIN + k];
}

// ---------------- pack aligned in-block triangles ----------------
__global__ __launch_bounds__(256) void pack_wmid(const float* __restrict__ Wmid,
                                                 const unsigned char* __restrict__ adjN,
                                                 float* __restrict__ wpack) {
  int g = blockIdx.x * 256 + threadIdx.x;  // 65536 float4s
  int i = g >> 12;
  int rem = g & 4095;
  int j = rem >> 5;
  int q4 = (rem & 31) * 4;
  int n0 = 1 + i * TBLK;
  int size = NN - 1 - n0;
  if (size > TBLK) size = TBLK;
  float w[4];
#pragma unroll
  for (int e = 0; e < 4; ++e) {
    int q = q4 + e;
    float v = 0.f;
    if (q > j && j < size && q < size) {
      size_t idx = (size_t)(n0 + j) * NN + (size_t)(n0 + q);
      v = Wmid[idx] * (float)adjN[idx];
    }
    w[e] = v;
  }
  *(float4*)(wpack + (size_t)g * 4) = make_float4(w[0], w[1], w[2], w[3]);
}

// ---------------- unified partial GEMM ----------------
// MODE 0: no mask. MODE 1: element mask. MODE 2: row mask (adj[:,NN-1]). All atomic acc.
template <int MODE>
__global__ __launch_bounds__(256) void gemm_partial(
    const float* __restrict__ AT, const float* __restrict__ W,
    const unsigned char* __restrict__ adj, float* __restrict__ accT,
    int ldw, int col0, int ncols, int kPerChunk, int nColTiles)
{
  const int ct = blockIdx.x % nColTiles;
  const int kc = blockIdx.x / nColTiles;
  const int c0 = ct * 64;
  const int k0 = kc * kPerChunk;
  const int t = threadIdx.x;
  const int tb = t >> 4;
  const int tc = t & 15;

  __shared__ __align__(16) float At[16][64];
  __shared__ __align__(16) float Wt[16][64];

  float acc[4][4] = {};
  const int sk = t >> 4;
  const int sq = t & 15;

  for (int ks = k0; ks < k0 + kPerChunk; ks += 16) {
    const float4 av = *(const float4*)(AT + (size_t)(ks + sk) * 64 + sq * 4);
    *(float4*)(&At[sk][sq * 4]) = av;
    {
      const float* wrow = W + (size_t)(ks + sk) * ldw + col0;
      float w[4];
      float rowmask = 1.f;
      if (MODE == 2) rowmask = (float)adj[(size_t)(ks + sk) * NN + (NN - 1)];
#pragma unroll
      for (int e = 0; e < 4; ++e) {
        int cl = c0 + sq * 4 + e;
        float wv = 0.f;
        if (cl < ncols) {
          wv = wrow[cl];
          if (MODE == 1) wv *= (float)adj[(size_t)(ks + sk) * NN + col0 + cl];
          if (MODE == 2) wv *= rowmask;
        }
        w[e] = wv;
      }
      *(float4*)(&Wt[sk][sq * 4]) = make_float4(w[0], w[1], w[2], w[3]);
    }
    __syncthreads();
#pragma unroll
    for (int kk = 0; kk < 16; ++kk) {
      float a4[4], w4[4];
#pragma unroll
      for (int e = 0; e < 4; ++e) a4[e] = At[kk][tb * 4 + e];
#pragma unroll
      for (int e = 0; e < 4; ++e) w4[e] = Wt[kk][tc * 4 + e];
#pragma unroll
      for (int i = 0; i < 4; ++i)
#pragma unroll
        for (int j = 0; j < 4; ++j) acc[i][j] = fmaf(a4[i], w4[j], acc[i][j]);
    }
    __syncthreads();
  }

#pragma unroll
  for (int j = 0; j < 4; ++j) {
    int cl = c0 + tc * 4 + j;
    if (cl < ncols) {
      float* dst = accT + (size_t)(col0 + cl) * 64 + tb * 4;
#pragma unroll
      for (int i = 0; i < 4; ++i) atomicAdd(dst + i, acc[i][j]);
    }
  }
}

// ---------------- init finish ----------------
__global__ void init_finish(const float* __restrict__ out0accT, const float* __restrict__ b0,
                            const unsigned char* __restrict__ adjN, const int* __restrict__ nl_idx,
                            float* __restrict__ curT) {
  int g = blockIdx.x * blockDim.x + threadIdx.x;
  int n = g >> 6;
  float v = out0accT[g] + b0[n];
  v = apply_nl(nl_idx[0], v);
  curT[g] = adjN[n] ? v : 0.f;
}

// ---------------- fused middle v2: 16 solver WGs + 240 helper WGs ----------------
// Solver bi: waits updDone[bi]==2*bi, loads corrected CbaseT, solves 128 steps
// (R6-proven structure), exports deltas, sets solveDone[bi].
// Helper (p,cj,half): junk-FMA spins on solveDone[p], then K=128 x 64-col masked
// GEMM CbaseT[cols of cj] += delta_p @ W, bumps updDone[cj].
__global__ __launch_bounds__(256, 1) void fused_mega(
    const float* __restrict__ wpack, const float* __restrict__ Wmid,
    const unsigned char* __restrict__ adjN, const int* __restrict__ nlidx,
    const float* __restrict__ bmid, float* __restrict__ CbaseT,
    float* __restrict__ curT, float* __restrict__ deltaG,
    int* solveDone, int* updDone)
{
  const int wg = blockIdx.x;
  const int tid = threadIdx.x;

  if (wg < NBLK) {
    // ================= SOLVER =================
    __shared__ __align__(16) float wmS[TBLK][TBLK];      // 64 KiB
    __shared__ __align__(16) float ivS[TBLK][64];        // 32 KiB
    __shared__ __align__(16) float deltaFull[TBLK][64];  // 32 KiB
    __shared__ int idS[TBLK];
    __shared__ int swf;

    const int bi = wg;
    const int n0 = 1 + bi * TBLK;
    int size = NN - 1 - n0;
    if (size > TBLK) size = TBLK;
    const int wv = tid >> 6;
    const int b = tid & 63;
    const int qbase = wv * 32;

    // ---- stage triangle + iv + id (independent of updates; early) ----
    {
      const float4* src = (const float4*)(wpack + (size_t)bi * TBLK * TBLK);
      float4 stg[16];
#pragma unroll
      for (int it = 0; it < 16; ++it) stg[it] = src[it * 256 + tid];
      const float4* ivsrc = (const float4*)(curT + (size_t)n0 * 64);
      float4 ivstg[8];
#pragma unroll
      for (int it = 0; it < 8; ++it) ivstg[it] = ivsrc[it * 256 + tid];
#pragma unroll
      for (int it = 0; it < 16; ++it) ((float4*)&wmS[0][0])[it * 256 + tid] = stg[it];
#pragma unroll
      for (int it = 0; it < 8; ++it) ((float4*)&ivS[0][0])[it * 256 + tid] = ivstg[it];
    }
    if (tid < TBLK) idS[tid] = (tid < size) ? nlidx[n0 + tid] : 3;
    float bm[32];
#pragma unroll
    for (int l = 0; l < 32; ++l) {
      int q = qbase + l;
      bm[l] = (q < size) ? bmid[n0 + q] : 0.f;
    }

    // ---- wait until all 2*bi cross-updates have landed in CbaseT ----
    {
      int done = 0, cnt = 0;
      const int need = 2 * bi;
      while (!done && cnt < 2000000) {
        if (tid == 0) swf = (atomicAdd(&updDone[bi], 0) >= need) ? 1 : 0;
        __syncthreads();
        done = swf;
        __syncthreads();
        ++cnt;
        if (!done) __builtin_amdgcn_s_sleep(4);
      }
    }
    __threadfence();  // acquire helpers' CbaseT writes

    // ---- load corrected pre-activations ----
    float val[32];
#pragma unroll
    for (int l = 0; l < 32; ++l) {
      int q = qbase + l;
      val[l] = (q < size) ? (CbaseT[(size_t)(n0 + q) * 64 + b] + bm[l]) : 0.f;
    }
    __syncthreads();

    // ---- 4-phase chunked triangular solve (R6-proven) ----
#pragma unroll 1
    for (int c = 0; c < 4; ++c) {
      if (wv == c) {
        const int jbase = c * 32;
        float4 wrow[8];
        {
          const float4* wr = (const float4*)(&wmS[jbase][qbase]);
#pragma unroll
          for (int g2 = 0; g2 < 8; ++g2) wrow[g2] = wr[g2];
        }
        float ivv = ivS[jbase][b];
        int idv = idS[jbase];
#pragma unroll
        for (int jj = 0; jj < 32; ++jj) {
          const int j = jbase + jj;
          float nv = apply_nl(__builtin_amdgcn_readfirstlane(idv), val[jj]);
          float delta = (j < size) ? (nv - ivv) : 0.f;
          deltaFull[j][b] = delta;
          float4 wnext[8];
          float ivn = 0.f;
          int idn = 3;
          if (jj < 31) {
            const float4* wr2 = (const float4*)(&wmS[j + 1][qbase]);
#pragma unroll
            for (int g2 = 0; g2 < 8; ++g2) wnext[g2] = wr2[g2];
            ivn = ivS[j + 1][b];
            idn = idS[j + 1];
          }
#pragma unroll
          for (int g2 = (jj + 1) >> 2; g2 < 8; ++g2) {
            if (g2 * 4 + 0 > jj) val[g2 * 4 + 0] = fmaf(delta, wrow[g2].x, val[g2 * 4 + 0]);
            if (g2 * 4 + 1 > jj) val[g2 * 4 + 1] = fmaf(delta, wrow[g2].y, val[g2 * 4 + 1]);
            if (g2 * 4 + 2 > jj) val[g2 * 4 + 2] = fmaf(delta, wrow[g2].z, val[g2 * 4 + 2]);
            if (g2 * 4 + 3 > jj) val[g2 * 4 + 3] = fmaf(delta, wrow[g2].w, val[g2 * 4 + 3]);
          }
          if (jj < 31) {
#pragma unroll
            for (int g2 = 0; g2 < 8; ++g2) wrow[g2] = wnext[g2];
            ivv = ivn;
            idv = idn;
          }
        }
      }
      __syncthreads();
      if (wv > c) {
#pragma unroll 1
        for (int jj = 0; jj < 32; ++jj) {
          const int j = c * 32 + jj;
          const float delta = deltaFull[j][b];
          const float4* wr = (const float4*)(&wmS[j][qbase]);
          float4 w0 = wr[0], w1 = wr[1], w2 = wr[2], w3 = wr[3];
          float4 w4 = wr[4], w5 = wr[5], w6 = wr[6], w7 = wr[7];
          val[0] = fmaf(delta, w0.x, val[0]);   val[1] = fmaf(delta, w0.y, val[1]);
          val[2] = fmaf(delta, w0.z, val[2]);   val[3] = fmaf(delta, w0.w, val[3]);
          val[4] = fmaf(delta, w1.x, val[4]);   val[5] = fmaf(delta, w1.y, val[5]);
          val[6] = fmaf(delta, w1.z, val[6]);   val[7] = fmaf(delta, w1.w, val[7]);
          val[8] = fmaf(delta, w2.x, val[8]);   val[9] = fmaf(delta, w2.y, val[9]);
          val[10] = fmaf(delta, w2.z, val[10]); val[11] = fmaf(delta, w2.w, val[11]);
          val[12] = fmaf(delta, w3.x, val[12]); val[13] = fmaf(delta, w3.y, val[13]);
          val[14] = fmaf(delta, w3.z, val[14]); val[15] = fmaf(delta, w3.w, val[15]);
          val[16] = fmaf(delta, w4.x, val[16]); val[17] = fmaf(delta, w4.y, val[17]);
          val[18] = fmaf(delta, w4.z, val[18]); val[19] = fmaf(delta, w4.w, val[19]);
          val[20] = fmaf(delta, w5.x, val[20]); val[21] = fmaf(delta, w5.y, val[21]);
          val[22] = fmaf(delta, w5.z, val[22]); val[23] = fmaf(delta, w5.w, val[23]);
          val[24] = fmaf(delta, w6.x, val[24]); val[25] = fmaf(delta, w6.y, val[25]);
          val[26] = fmaf(delta, w6.z, val[26]); val[27] = fmaf(delta, w6.w, val[27]);
          val[28] = fmaf(delta, w7.x, val[28]); val[29] = fmaf(delta, w7.y, val[29]);
          val[30] = fmaf(delta, w7.z, val[30]); val[31] = fmaf(delta, w7.w, val[31]);
        }
      }
      __syncthreads();
    }

    // ---- write results: curT (new state) + deltaG export ----
    {
      const float4* sdel = (const float4*)&deltaFull[0][0];
      const float4* siv = (const float4*)&ivS[0][0];
      float4* dstD = (float4*)(deltaG + (size_t)bi * TBLK * 64);
      float4* dstC = (float4*)(curT + (size_t)n0 * 64);
#pragma unroll
      for (int it = 0; it < 8; ++it) {
        int v = it * 256 + tid;
        float4 d = sdel[v];
        dstD[v] = d;
        int r = v >> 4;
        if (r < size) {
          float4 ivv4 = siv[v];
          dstC[v] = make_float4(d.x + ivv4.x, d.y + ivv4.y, d.z + ivv4.z, d.w + ivv4.w);
        }
      }
    }
    __threadfence();
    __syncthreads();
    if (tid == 0) atomicExch(&solveDone[bi], 1);

  } else {
    // ================= HELPER =================
    __shared__ __align__(16) float At[16][64];
    __shared__ __align__(16) float Wt[16][64];
    __shared__ int sfl;

    int t2 = (wg - NBLK) >> 1;     // pair index 0..119
    const int half = (wg - NBLK) & 1;
    int p = 0;
    while (t2 >= NBLK - 1 - p) { t2 -= NBLK - 1 - p; ++p; }
    const int cj = p + 1 + t2;
    const int rowbase = 1 + p * TBLK;
    const int n0c = 1 + cj * TBLK;
    const int col0 = n0c + half * 64;
    int ncols = (NN - 1) - col0;
    if (ncols > 64) ncols = 64;

    // ---- junk-FMA spin on producer's flag (keeps clocks up; bounded) ----
    {
      float jx = 1.0f + (float)tid * 1e-6f;
      const float jy = 0.4999999f;
      int done = 0, cnt = 0;
      while (!done && cnt < 1000000) {
#pragma unroll
        for (int i = 0; i < 64; ++i) jx = fmaf(jx, 1.0000001f, jy);
        if (tid == 0) sfl = atomicAdd(&solveDone[p], 0);
        __syncthreads();
        done = sfl;
        __syncthreads();
        ++cnt;
      }
      asm volatile("" ::"v"(jx));  // keep junk alive (rule #17)
    }
    __threadfence();  // acquire producer's deltaG

    // ---- K=128 masked GEMM: CbaseT[cols] += delta_p @ (W*adj) ----
    const float* AT = deltaG + (size_t)p * TBLK * 64;
    const int tb = tid >> 4;
    const int tc = tid & 15;
    const int sk = tid >> 4;
    const int sq = tid & 15;
    float acc[4][4] = {};
    for (int ks = 0; ks < TBLK; ks += 16) {
      const float4 av = *(const float4*)(AT + (size_t)(ks + sk) * 64 + sq * 4);
      *(float4*)(&At[sk][sq * 4]) = av;
      {
        const float* wrow = Wmid + (size_t)(rowbase + ks + sk) * NN + col0;
        const unsigned char* arow = adjN + (size_t)(rowbase + ks + sk) * NN + col0;
        float w[4];
#pragma unroll
        for (int e = 0; e < 4; ++e) {
          int cl = sq * 4 + e;
          w[e] = (cl < ncols) ? wrow[cl] * (float)arow[cl] : 0.f;
        }
        *(float4*)(&Wt[sk][sq * 4]) = make_float4(w[0], w[1], w[2], w[3]);
      }
      __syncthreads();
#pragma unroll
      for (int kk = 0; kk < 16; ++kk) {
        float a4[4], w4[4];
#pragma unroll
        for (int e = 0; e < 4; ++e) a4[e] = At[kk][tb * 4 + e];
#pragma unroll
        for (int e = 0; e < 4; ++e) w4[e] = Wt[kk][tc * 4 + e];
#pragma unroll
        for (int i = 0; i < 4; ++i)
#pragma unroll
          for (int j = 0; j < 4; ++j) acc[i][j] = fmaf(a4[i], w4[j], acc[i][j]);
      }
      __syncthreads();
    }
#pragma unroll
    for (int j = 0; j < 4; ++j) {
      int cl = tc * 4 + j;
      if (cl < ncols) {
        float* dst = CbaseT + (size_t)(col0 + cl) * 64 + tb * 4;
#pragma unroll
        for (int i = 0; i < 4; ++i) atomicAdd(dst + i, acc[i][j]);
      }
    }
    __threadfence();  // release our CbaseT adds
    __syncthreads();
    if (tid == 0) atomicAdd(&updDone[cj], 1);
  }
}

// ---------------- final finish ----------------
__global__ void final_finish(const float* __restrict__ outaccT, const float* __restrict__ bout,
                             const int* __restrict__ nlidx, float* __restrict__ out) {
  int g = blockIdx.x * blockDim.x + threadIdx.x;
  int c = g >> 6, b = g & 63;
  float v = outaccT[g] + bout[c];
  v = apply_nl(nlidx[NN - 1], v);
  out[(size_t)b * DOUT + c] = v;
}

// ---------------- state transpose ----------------
__global__ __launch_bounds__(256) void transpose_state(const float* __restrict__ curT,
                                                       float* __restrict__ stateOut) {
  __shared__ float tile[64][65];
  int n0 = blockIdx.x * 64;
  for (int r = 0; r < 16; ++r) {
    int e = r * 256 + threadIdx.x;
    tile[e >> 6][e & 63] = curT[(size_t)(n0 + (e >> 6)) * 64 + (e & 63)];
  }
  __syncthreads();
  for (int r = 0; r < 16; ++r) {
    int e = r * 256 + threadIdx.x;
    int bb = e >> 6, nn2 = e & 63;
    stateOut[(size_t)bb * NN + n0 + nn2] = tile[nn2][bb];
  }
}

extern "C" void kernel_launch(void* const* d_in, const int* in_sizes, int n_in,
                              void* d_out, int out_size, void* d_ws, size_t ws_size,
                              hipStream_t stream) {
  const float* X = (const float*)d_in[0];
  const unsigned char* adj = (const unsigned char*)d_in[1];
  const int* nl_idx = (const int*)d_in[2];
  const float* W0 = (const float*)d_in[3];
  const float* b0 = (const float*)d_in[4];
  const float* W_mid = (const float*)d_in[5];
  const float* b_mid = (const float*)d_in[6];
  const float* W_out = (const float*)d_in[7];
  const float* b_out = (const float*)d_in[8];
  float* out = (float*)d_out;
  float* stateOut = out + BN * DOUT;

  char* ws = (char*)d_ws;
  unsigned char* adjN = (unsigned char*)(ws + 0);       // 4 MiB
  int* flags = (int*)(ws + 4194304);                    // 256 B: [0..1]=detect, [8..23]=solveDone, [24..39]=updDone
  float* XT = (float*)(ws + 4194560);                   // 256 KiB
  float* curT = (float*)(ws + 4456704);                 // 512 KiB
  float* CbaseT = (float*)(ws + 4980992);               // 512 KiB (zeroed acc, updated in place)
  float* out0accT = (float*)(ws + 5505280);             // 512 KiB (zeroed acc)
  float* outaccT = (float*)(ws + 6029568);              // 128 KiB (zeroed acc)
  float* wpack = (float*)(ws + 6160640);                // 1 MiB
  float* deltaG = (float*)(ws + 7209216);               // 512 KiB -> end 7733504
  int* solveDone = flags + 8;
  int* updDone = flags + 24;

  hipMemsetAsync(flags, 0, 256, stream);
  hipMemsetAsync(CbaseT, 0, 524288 + 524288 + 131072, stream);

  detect_adj<<<64, 256, 0, stream>>>((const unsigned int*)adj, flags);
  normalize_adj<<<16384, 256, 0, stream>>>(adj, flags, adjN);
  transpose_x<<<256, 256, 0, stream>>>(X, XT);
  pack_wmid<<<256, 256, 0, stream>>>(W_mid, adjN, wpack);

  // node 0: out0accT = X @ W0
  gemm_partial<0><<<128, 256, 0, stream>>>(XT, W0, adjN, out0accT, NN, 0, NN, 256, 32);
  init_finish<<<512, 256, 0, stream>>>(out0accT, b0, adjN, nl_idx, curT);

  // Cbase: state_0 @ (W_mid * adj) for ALL columns (one big parallel GEMM)
  gemm_partial<1><<<256, 256, 0, stream>>>(curT, W_mid, adjN, CbaseT, NN, 0, NN, 256, 32);

  // entire sequential middle in ONE persistent dispatch (16 solvers + 240 helpers)
  fused_mega<<<256, 256, 0, stream>>>(wpack, W_mid, adjN, nl_idx, b_mid, CbaseT,
                                      curT, deltaG, solveDone, updDone);

  gemm_partial<2><<<64, 256, 0, stream>>>(curT, W_out, adjN, outaccT, DOUT, 0, DOUT, 256, 8);
  final_finish<<<128, 256, 0, stream>>>(outaccT, b_out, nl_idx, out);
  transpose_state<<<32, 256, 0, stream>>>(curT, stateOut);
}

// Round 10
// 965.219 us; speedup vs baseline: 1.3162x; 1.1853x over previous
//
#include <hip/hip_runtime.h>
#include <math.h>

#define BN 64
#define KIN 1024
#define DOUT 512
#define NN 2048
#define TBLK 128
#define NBLK 16

__device__ __forceinline__ float softplus_f(float x) {
  float e = __expf(-fabsf(x));
  return fmaxf(x, 0.f) + __logf(1.f + e);
}
__device__ __forceinline__ float apply_nl(int id, float v) {
  switch (id) {
    case 0: return fmaxf(v, 0.f);
    case 1: { float e = __expf(2.f * v); return fmaf(-2.f, __builtin_amdgcn_rcpf(e + 1.f), 1.f); }
    case 2: return v >= 0.f ? v : 0.01f * v;
    case 3: return v;
    case 4: return __sinf(v);
    case 5: return softplus_f(v);
    default: return v - softplus_f(v);  // -softplus(-v)
  }
}

// Pipelined branchless nl: candidates computed one step early, select is a cndmask tree.
__device__ __forceinline__ void nl_cand(float v, float& mx, float& th, float& lk,
                                        float& sn, float& sp, float& sm) {
  mx = fmaxf(v, 0.f);
  lk = fmaf(fminf(v, 0.f), 0.01f, mx);
  float e = __expf(-fabsf(v));
  float e2 = e * e;
  float l1 = __logf(1.f + e);
  sp = mx + l1;
  sm = v - sp;
  th = __builtin_copysignf((1.f - e2) * __builtin_amdgcn_rcpf(1.f + e2), v);
  sn = __sinf(v);
}
__device__ __forceinline__ float nl_sel(int id, float v, float mx, float th, float lk,
                                        float sn, float sp, float sm) {
  float r = v;
  r = (id == 0) ? mx : r;
  r = (id == 1) ? th : r;
  r = (id == 2) ? lk : r;
  r = (id == 4) ? sn : r;
  r = (id == 5) ? sp : r;
  r = (id == 6) ? sm : r;
  return r;
}

// element l (compile-time after unroll) of a float4[8] register row
#define WEL(arr, l) (((l) & 3) == 0 ? arr[(l) >> 2].x : ((l) & 3) == 1 ? arr[(l) >> 2].y \
                     : ((l) & 3) == 2 ? arr[(l) >> 2].z : arr[(l) >> 2].w)

// ---------------- adj dtype detection (parallel) ----------------
__global__ void detect_adj(const unsigned int* __restrict__ a, int* __restrict__ flags) {
  int idx = blockIdx.x * 256 + threadIdx.x;  // 16384 dwords = first 64 KiB
  unsigned int v = a[idx];
  bool bad = ((v & 0xFFu) > 1u) || (((v >> 8) & 0xFFu) > 1u) ||
             (((v >> 16) & 0xFFu) > 1u) || ((v >> 24) > 1u);
  bool off = (v & 0xFFFFFF00u) != 0u;
  if (__any(bad) && (threadIdx.x & 63) == 0) atomicOr(&flags[0], 1);
  if (__any(off) && (threadIdx.x & 63) == 0) atomicOr(&flags[1], 1);
}

__global__ void normalize_adj(const unsigned char* __restrict__ a,
                              const int* __restrict__ flags,
                              unsigned char* __restrict__ out) {
  size_t i = (size_t)blockIdx.x * blockDim.x + threadIdx.x;
  int mode = flags[0] ? 2 : (flags[1] ? 1 : 0);
  unsigned char r;
  if (mode == 1)      r = (a[i] != 0);
  else if (mode == 0) r = (((const int*)a)[i] != 0);
  else                r = (((const float*)a)[i] != 0.f);
  out[i] = r;
}

// ---------------- X transpose ----------------
__global__ void transpose_x(const float* __restrict__ X, float* __restrict__ XT) {
  int g = blockIdx.x * blockDim.x + threadIdx.x;
  int k = g >> 6, b = g & 63;
  XT[g] = X[(size_t)b * KIN + k];
}

// ---------------- pack aligned in-block triangles ----------------
__global__ __launch_bounds__(256) void pack_wmid(const float* __restrict__ Wmid,
                                                 const unsigned char* __restrict__ adjN,
                                                 float* __restrict__ wpack) {
  int g = blockIdx.x * 256 + threadIdx.x;  // 65536 float4s
  int i = g >> 12;
  int rem = g & 4095;
  int j = rem >> 5;
  int q4 = (rem & 31) * 4;
  int n0 = 1 + i * TBLK;
  int size = NN - 1 - n0;
  if (size > TBLK) size = TBLK;
  float w[4];
#pragma unroll
  for (int e = 0; e < 4; ++e) {
    int q = q4 + e;
    float v = 0.f;
    if (q > j && j < size && q < size) {
      size_t idx = (size_t)(n0 + j) * NN + (size_t)(n0 + q);
      v = Wmid[idx] * (float)adjN[idx];
    }
    w[e] = v;
  }
  *(float4*)(wpack + (size_t)g * 4) = make_float4(w[0], w[1], w[2], w[3]);
}

// ---------------- unified partial GEMM ----------------
template <int MODE>
__global__ __launch_bounds__(256) void gemm_partial(
    const float* __restrict__ AT, const float* __restrict__ W,
    const unsigned char* __restrict__ adj, float* __restrict__ accT,
    int ldw, int col0, int ncols, int kPerChunk, int nColTiles)
{
  const int ct = blockIdx.x % nColTiles;
  const int kc = blockIdx.x / nColTiles;
  const int c0 = ct * 64;
  const int k0 = kc * kPerChunk;
  const int t = threadIdx.x;
  const int tb = t >> 4;
  const int tc = t & 15;

  __shared__ __align__(16) float At[16][64];
  __shared__ __align__(16) float Wt[16][64];

  float acc[4][4] = {};
  const int sk = t >> 4;
  const int sq = t & 15;

  for (int ks = k0; ks < k0 + kPerChunk; ks += 16) {
    const float4 av = *(const float4*)(AT + (size_t)(ks + sk) * 64 + sq * 4);
    *(float4*)(&At[sk][sq * 4]) = av;
    {
      const float* wrow = W + (size_t)(ks + sk) * ldw + col0;
      float w[4];
      float rowmask = 1.f;
      if (MODE == 2) rowmask = (float)adj[(size_t)(ks + sk) * NN + (NN - 1)];
#pragma unroll
      for (int e = 0; e < 4; ++e) {
        int cl = c0 + sq * 4 + e;
        float wv = 0.f;
        if (cl < ncols) {
          wv = wrow[cl];
          if (MODE == 1) wv *= (float)adj[(size_t)(ks + sk) * NN + col0 + cl];
          if (MODE == 2) wv *= rowmask;
        }
        w[e] = wv;
      }
      *(float4*)(&Wt[sk][sq * 4]) = make_float4(w[0], w[1], w[2], w[3]);
    }
    __syncthreads();
#pragma unroll
    for (int kk = 0; kk < 16; ++kk) {
      float a4[4], w4[4];
#pragma unroll
      for (int e = 0; e < 4; ++e) a4[e] = At[kk][tb * 4 + e];
#pragma unroll
      for (int e = 0; e < 4; ++e) w4[e] = Wt[kk][tc * 4 + e];
#pragma unroll
      for (int i = 0; i < 4; ++i)
#pragma unroll
        for (int j = 0; j < 4; ++j) acc[i][j] = fmaf(a4[i], w4[j], acc[i][j]);
    }
    __syncthreads();
  }

#pragma unroll
  for (int j = 0; j < 4; ++j) {
    int cl = c0 + tc * 4 + j;
    if (cl < ncols) {
      float* dst = accT + (size_t)(col0 + cl) * 64 + tb * 4;
#pragma unroll
      for (int i = 0; i < 4; ++i) atomicAdd(dst + i, acc[i][j]);
    }
  }
}

// ---------------- init finish ----------------
__global__ void init_finish(const float* __restrict__ out0accT, const float* __restrict__ b0,
                            const unsigned char* __restrict__ adjN, const int* __restrict__ nl_idx,
                            float* __restrict__ curT) {
  int g = blockIdx.x * blockDim.x + threadIdx.x;
  int n = g >> 6;
  float v = out0accT[g] + b0[n];
  v = apply_nl(nl_idx[0], v);
  curT[g] = adjN[n] ? v : 0.f;
}

// ---------------- fused middle v3: pipelined-nl solvers + prestaging helpers ----------
// Shared-memory arena overlaid between the two roles (mutually exclusive per WG):
//   solver: wmS 64K | ivS 32K | deltaFull 32K | idS 512 | swf 4      = ~128.6 KiB
//   helper: Wslab 32K | At 4K | sfl 4                                = ~36 KiB
__global__ __launch_bounds__(256, 1) void fused_mega(
    const float* __restrict__ wpack, const float* __restrict__ Wmid,
    const unsigned char* __restrict__ adjN, const int* __restrict__ nlidx,
    const float* __restrict__ bmid, float* __restrict__ CbaseT,
    float* __restrict__ curT, float* __restrict__ deltaG,
    int* solveDone, int* updDone)
{
  __shared__ __align__(16) unsigned char smem[132096];  // 129 KiB arena
  const int wg = blockIdx.x;
  const int tid = threadIdx.x;

  if (wg < NBLK) {
    // ================= SOLVER =================
    float (*wmS)[TBLK]     = (float(*)[TBLK])(smem);            // 64 KiB
    float (*ivS)[64]       = (float(*)[64])(smem + 65536);      // 32 KiB
    float (*deltaFull)[64] = (float(*)[64])(smem + 98304);      // 32 KiB
    int* idS               = (int*)(smem + 131072);             // 512 B
    int* swf               = (int*)(smem + 131584);

    const int bi = wg;
    const int n0 = 1 + bi * TBLK;
    int size = NN - 1 - n0;
    if (size > TBLK) size = TBLK;
    const int wv = tid >> 6;
    const int b = tid & 63;
    const int qbase = wv * 32;

    // ---- stage triangle + iv + id early (independent of cross-updates) ----
    {
      const float4* src = (const float4*)(wpack + (size_t)bi * TBLK * TBLK);
      float4 stg[16];
#pragma unroll
      for (int it = 0; it < 16; ++it) stg[it] = src[it * 256 + tid];
      const float4* ivsrc = (const float4*)(curT + (size_t)n0 * 64);
      float4 ivstg[8];
#pragma unroll
      for (int it = 0; it < 8; ++it) ivstg[it] = ivsrc[it * 256 + tid];
#pragma unroll
      for (int it = 0; it < 16; ++it) ((float4*)&wmS[0][0])[it * 256 + tid] = stg[it];
#pragma unroll
      for (int it = 0; it < 8; ++it) ((float4*)&ivS[0][0])[it * 256 + tid] = ivstg[it];
    }
    if (tid < TBLK) idS[tid] = (tid < size) ? nlidx[n0 + tid] : 3;
    float bm[32];
#pragma unroll
    for (int l = 0; l < 32; ++l) {
      int q = qbase + l;
      bm[l] = (q < size) ? bmid[n0 + q] : 0.f;
    }

    // ---- wait for all 2*bi cross-updates ----
    {
      int done = 0, cnt = 0;
      const int need = 2 * bi;
      while (!done && cnt < 2000000) {
        if (tid == 0) *swf = (atomicAdd(&updDone[bi], 0) >= need) ? 1 : 0;
        __syncthreads();
        done = *swf;
        __syncthreads();
        ++cnt;
        if (!done) __builtin_amdgcn_s_sleep(2);
      }
    }
    __threadfence();

    // ---- load corrected pre-activations ----
    float val[32];
#pragma unroll
    for (int l = 0; l < 32; ++l) {
      int q = qbase + l;
      val[l] = (q < size) ? (CbaseT[(size_t)(n0 + q) * 64 + b] + bm[l]) : 0.f;
    }
    __syncthreads();

    // ---- 4-phase chunked triangular solve, pipelined-nl Phase A ----
#pragma unroll 1
    for (int c = 0; c < 4; ++c) {
      if (wv == c) {
        const int jbase = c * 32;
        float4 wrow[8];
        {
          const float4* wr = (const float4*)(&wmS[jbase][qbase]);
#pragma unroll
          for (int g2 = 0; g2 < 8; ++g2) wrow[g2] = wr[g2];
        }
        float ivv = ivS[jbase][b];
        int idv = idS[jbase];
        float cmx, cth, clk, csn, csp, csm;
        nl_cand(val[0], cmx, cth, clk, csn, csp, csm);
#pragma unroll
        for (int jj = 0; jj < 32; ++jj) {
          const int j = jbase + jj;
          float nv = nl_sel(idv, val[jj], cmx, cth, clk, csn, csp, csm);
          float delta = (j < size) ? (nv - ivv) : 0.f;
          deltaFull[j][b] = delta;
          float4 wnext[8];
          float ivn = 0.f;
          int idn = 3;
          if (jj < 31) {
            const float4* wr2 = (const float4*)(&wmS[j + 1][qbase]);
#pragma unroll
            for (int g2 = (jj + 2) >> 2; g2 < 8; ++g2) wnext[g2] = wr2[g2];
            ivn = ivS[j + 1][b];
            idn = idS[j + 1];
            // critical-first: finalize next slot, launch its candidates early
            val[jj + 1] = fmaf(delta, WEL(wrow, (jj + 1)), val[jj + 1]);
            nl_cand(val[jj + 1], cmx, cth, clk, csn, csp, csm);
          }
#pragma unroll
          for (int l = jj + 2; l < 32; ++l)
            val[l] = fmaf(delta, WEL(wrow, l), val[l]);
          if (jj < 31) {
#pragma unroll
            for (int g2 = 0; g2 < 8; ++g2) wrow[g2] = wnext[g2];
            ivv = ivn;
            idv = idn;
          }
        }
      }
      __syncthreads();
      if (wv > c) {
#pragma unroll 1
        for (int jj = 0; jj < 32; ++jj) {
          const int j = c * 32 + jj;
          const float delta = deltaFull[j][b];
          const float4* wr = (const float4*)(&wmS[j][qbase]);
          float4 w0 = wr[0], w1 = wr[1], w2 = wr[2], w3 = wr[3];
          float4 w4 = wr[4], w5 = wr[5], w6 = wr[6], w7 = wr[7];
          val[0] = fmaf(delta, w0.x, val[0]);   val[1] = fmaf(delta, w0.y, val[1]);
          val[2] = fmaf(delta, w0.z, val[2]);   val[3] = fmaf(delta, w0.w, val[3]);
          val[4] = fmaf(delta, w1.x, val[4]);   val[5] = fmaf(delta, w1.y, val[5]);
          val[6] = fmaf(delta, w1.z, val[6]);   val[7] = fmaf(delta, w1.w, val[7]);
          val[8] = fmaf(delta, w2.x, val[8]);   val[9] = fmaf(delta, w2.y, val[9]);
          val[10] = fmaf(delta, w2.z, val[10]); val[11] = fmaf(delta, w2.w, val[11]);
          val[12] = fmaf(delta, w3.x, val[12]); val[13] = fmaf(delta, w3.y, val[13]);
          val[14] = fmaf(delta, w3.z, val[14]); val[15] = fmaf(delta, w3.w, val[15]);
          val[16] = fmaf(delta, w4.x, val[16]); val[17] = fmaf(delta, w4.y, val[17]);
          val[18] = fmaf(delta, w4.z, val[18]); val[19] = fmaf(delta, w4.w, val[19]);
          val[20] = fmaf(delta, w5.x, val[20]); val[21] = fmaf(delta, w5.y, val[21]);
          val[22] = fmaf(delta, w5.z, val[22]); val[23] = fmaf(delta, w5.w, val[23]);
          val[24] = fmaf(delta, w6.x, val[24]); val[25] = fmaf(delta, w6.y, val[25]);
          val[26] = fmaf(delta, w6.z, val[26]); val[27] = fmaf(delta, w6.w, val[27]);
          val[28] = fmaf(delta, w7.x, val[28]); val[29] = fmaf(delta, w7.y, val[29]);
          val[30] = fmaf(delta, w7.z, val[30]); val[31] = fmaf(delta, w7.w, val[31]);
        }
      }
      __syncthreads();
    }

    // ---- write results: curT + deltaG export ----
    {
      const float4* sdel = (const float4*)&deltaFull[0][0];
      const float4* siv = (const float4*)&ivS[0][0];
      float4* dstD = (float4*)(deltaG + (size_t)bi * TBLK * 64);
      float4* dstC = (float4*)(curT + (size_t)n0 * 64);
#pragma unroll
      for (int it = 0; it < 8; ++it) {
        int v = it * 256 + tid;
        float4 d = sdel[v];
        dstD[v] = d;
        int r = v >> 4;
        if (r < size) {
          float4 ivv4 = siv[v];
          dstC[v] = make_float4(d.x + ivv4.x, d.y + ivv4.y, d.z + ivv4.z, d.w + ivv4.w);
        }
      }
    }
    __threadfence();
    __syncthreads();
    if (tid == 0) atomicExch(&solveDone[bi], 1);

  } else {
    // ================= HELPER =================
    float (*Wslab)[64] = (float(*)[64])(smem);                // 32 KiB
    float (*At)[64]    = (float(*)[64])(smem + 32768);        // 4 KiB
    int* sfl           = (int*)(smem + 36864);

    int t2 = (wg - NBLK) >> 1;     // pair index 0..119
    const int half = (wg - NBLK) & 1;
    int p = 0;
    while (t2 >= NBLK - 1 - p) { t2 -= NBLK - 1 - p; ++p; }
    const int cj = p + 1 + t2;
    const int rowbase = 1 + p * TBLK;
    const int col0 = 1 + cj * TBLK + half * 64;
    int ncols = (NN - 1) - col0;
    if (ncols > 64) ncols = 64;

    // ---- prestage masked W slab into LDS during producer's solve ----
    {
      const int r0 = tid >> 4;
      const int c4 = (tid & 15) * 4;
      for (int ch = 0; ch < 8; ++ch) {
        int r = ch * 16 + r0;
        const float* wrow = Wmid + (size_t)(rowbase + r) * NN + col0;
        const unsigned char* arow = adjN + (size_t)(rowbase + r) * NN + col0;
        float w[4];
#pragma unroll
        for (int e = 0; e < 4; ++e) {
          int cl = c4 + e;
          w[e] = (cl < ncols) ? wrow[cl] * (float)arow[cl] : 0.f;
        }
        *(float4*)(&Wslab[r][c4]) = make_float4(w[0], w[1], w[2], w[3]);
      }
    }

    // ---- junk-FMA spin on producer's flag (clock pressure; bounded) ----
    {
      float jx = 1.0f + (float)tid * 1e-6f;
      int done = 0, cnt = 0;
      while (!done && cnt < 1000000) {
#pragma unroll
        for (int i = 0; i < 64; ++i) jx = fmaf(jx, 1.0000001f, 0.4999999f);
        if (tid == 0) *sfl = atomicAdd(&solveDone[p], 0);
        __syncthreads();
        done = *sfl;
        __syncthreads();
        ++cnt;
      }
      asm volatile("" ::"v"(jx));  // keep junk alive
    }
    __threadfence();

    // ---- K=128 GEMM: CbaseT[cols] += delta_p @ Wslab (LDS-resident) ----
    const float* AT = deltaG + (size_t)p * TBLK * 64;
    const int tb = tid >> 4;
    const int tc = tid & 15;
    const int sk = tid >> 4;
    const int sq = tid & 15;
    float acc[4][4] = {};
    for (int ks = 0; ks < TBLK; ks += 16) {
      *(float4*)(&At[sk][sq * 4]) = *(const float4*)(AT + (size_t)(ks + sk) * 64 + sq * 4);
      __syncthreads();
#pragma unroll
      for (int kk = 0; kk < 16; ++kk) {
        float a4[4], w4[4];
#pragma unroll
        for (int e = 0; e < 4; ++e) a4[e] = At[kk][tb * 4 + e];
#pragma unroll
        for (int e = 0; e < 4; ++e) w4[e] = Wslab[ks + kk][tc * 4 + e];
#pragma unroll
        for (int i = 0; i < 4; ++i)
#pragma unroll
          for (int jy = 0; jy < 4; ++jy) acc[i][jy] = fmaf(a4[i], w4[jy], acc[i][jy]);
      }
      __syncthreads();
    }
#pragma unroll
    for (int jy = 0; jy < 4; ++jy) {
      int cl = tc * 4 + jy;
      if (cl < ncols) {
        float* dst = CbaseT + (size_t)(col0 + cl) * 64 + tb * 4;
#pragma unroll
        for (int i = 0; i < 4; ++i) atomicAdd(dst + i, acc[i][jy]);
      }
    }
    __threadfence();
    __syncthreads();
    if (tid == 0) atomicAdd(&updDone[cj], 1);
  }
}

// ---------------- final finish ----------------
__global__ void final_finish(const float* __restrict__ outaccT, const float* __restrict__ bout,
                             const int* __restrict__ nlidx, float* __restrict__ out) {
  int g = blockIdx.x * blockDim.x + threadIdx.x;
  int c = g >> 6, b = g & 63;
  float v = outaccT[g] + bout[c];
  v = apply_nl(nlidx[NN - 1], v);
  out[(size_t)b * DOUT + c] = v;
}

// ---------------- state transpose ----------------
__global__ __launch_bounds__(256) void transpose_state(const float* __restrict__ curT,
                                                       float* __restrict__ stateOut) {
  __shared__ float tile[64][65];
  int n0 = blockIdx.x * 64;
  for (int r = 0; r < 16; ++r) {
    int e = r * 256 + threadIdx.x;
    tile[e >> 6][e & 63] = curT[(size_t)(n0 + (e >> 6)) * 64 + (e & 63)];
  }
  __syncthreads();
  for (int r = 0; r < 16; ++r) {
    int e = r * 256 + threadIdx.x;
    int bb = e >> 6, nn2 = e & 63;
    stateOut[(size_t)bb * NN + n0 + nn2] = tile[nn2][bb];
  }
}

extern "C" void kernel_launch(void* const* d_in, const int* in_sizes, int n_in,
                              void* d_out, int out_size, void* d_ws, size_t ws_size,
                              hipStream_t stream) {
  const float* X = (const float*)d_in[0];
  const unsigned char* adj = (const unsigned char*)d_in[1];
  const int* nl_idx = (const int*)d_in[2];
  const float* W0 = (const float*)d_in[3];
  const float* b0 = (const float*)d_in[4];
  const float* W_mid = (const float*)d_in[5];
  const float* b_mid = (const float*)d_in[6];
  const float* W_out = (const float*)d_in[7];
  const float* b_out = (const float*)d_in[8];
  float* out = (float*)d_out;
  float* stateOut = out + BN * DOUT;

  char* ws = (char*)d_ws;
  unsigned char* adjN = (unsigned char*)(ws + 0);       // 4 MiB
  int* flags = (int*)(ws + 4194304);                    // 256 B
  float* XT = (float*)(ws + 4194560);                   // 256 KiB
  float* curT = (float*)(ws + 4456704);                 // 512 KiB
  float* CbaseT = (float*)(ws + 4980992);               // 512 KiB
  float* out0accT = (float*)(ws + 5505280);             // 512 KiB
  float* outaccT = (float*)(ws + 6029568);              // 128 KiB
  float* wpack = (float*)(ws + 6160640);                // 1 MiB
  float* deltaG = (float*)(ws + 7209216);               // 512 KiB
  int* solveDone = flags + 8;
  int* updDone = flags + 24;

  hipMemsetAsync(flags, 0, 256, stream);
  hipMemsetAsync(CbaseT, 0, 524288 + 524288 + 131072, stream);

  detect_adj<<<64, 256, 0, stream>>>((const unsigned int*)adj, flags);
  normalize_adj<<<16384, 256, 0, stream>>>(adj, flags, adjN);
  transpose_x<<<256, 256, 0, stream>>>(X, XT);
  pack_wmid<<<256, 256, 0, stream>>>(W_mid, adjN, wpack);

  gemm_partial<0><<<128, 256, 0, stream>>>(XT, W0, adjN, out0accT, NN, 0, NN, 256, 32);
  init_finish<<<512, 256, 0, stream>>>(out0accT, b0, adjN, nl_idx, curT);

  gemm_partial<1><<<256, 256, 0, stream>>>(curT, W_mid, adjN, CbaseT, NN, 0, NN, 256, 32);

  fused_mega<<<256, 256, 0, stream>>>(wpack, W_mid, adjN, nl_idx, b_mid, CbaseT,
                                      curT, deltaG, solveDone, updDone);

  gemm_partial<2><<<64, 256, 0, stream>>>(curT, W_out, adjN, outaccT, DOUT, 0, DOUT, 256, 8);
  final_finish<<<128, 256, 0, stream>>>(outaccT, b_out, nl_idx, out);
  transpose_state<<<32, 256, 0, stream>>>(curT, stateOut);
}

// Round 11
// 870.525 us; speedup vs baseline: 1.4593x; 1.1088x over previous
//
#include <hip/hip_runtime.h>
#include <math.h>

#define BN 64
#define KIN 1024
#define DOUT 512
#define NN 2048
#define TBLK 128
#define NBLK 16

__device__ __forceinline__ float softplus_f(float x) {
  float e = __expf(-fabsf(x));
  return fmaxf(x, 0.f) + __logf(1.f + e);
}
__device__ __forceinline__ float apply_nl(int id, float v) {
  switch (id) {
    case 0: return fmaxf(v, 0.f);
    case 1: { float e = __expf(2.f * v); return fmaf(-2.f, __builtin_amdgcn_rcpf(e + 1.f), 1.f); }
    case 2: return v >= 0.f ? v : 0.01f * v;
    case 3: return v;
    case 4: return __sinf(v);
    case 5: return softplus_f(v);
    default: return v - softplus_f(v);  // -softplus(-v)
  }
}

// Pipelined branchless nl: candidates computed early, select is a cndmask tree.
__device__ __forceinline__ void nl_cand(float v, float& mx, float& th, float& lk,
                                        float& sn, float& sp, float& sm) {
  mx = fmaxf(v, 0.f);
  lk = fmaf(fminf(v, 0.f), 0.01f, mx);
  float e = __expf(-fabsf(v));
  float e2 = e * e;
  float l1 = __logf(1.f + e);
  sp = mx + l1;
  sm = v - sp;
  th = __builtin_copysignf((1.f - e2) * __builtin_amdgcn_rcpf(1.f + e2), v);
  sn = __sinf(v);
}
__device__ __forceinline__ float nl_sel(int id, float v, float mx, float th, float lk,
                                        float sn, float sp, float sm) {
  float r = v;
  r = (id == 0) ? mx : r;
  r = (id == 1) ? th : r;
  r = (id == 2) ? lk : r;
  r = (id == 4) ? sn : r;
  r = (id == 5) ? sp : r;
  r = (id == 6) ? sm : r;
  return r;
}

// element (m-row, l-col) of per-sub triangle regs tw[16] (float4 pairs per row)
#define TWEL(tw, m, l) (((l) & 3) == 0 ? tw[(m)*2 + ((l) >> 2)].x : \
                        ((l) & 3) == 1 ? tw[(m)*2 + ((l) >> 2)].y : \
                        ((l) & 3) == 2 ? tw[(m)*2 + ((l) >> 2)].z : tw[(m)*2 + ((l) >> 2)].w)

// ---------------- adj dtype detection (parallel) ----------------
__global__ void detect_adj(const unsigned int* __restrict__ a, int* __restrict__ flags) {
  int idx = blockIdx.x * 256 + threadIdx.x;  // 16384 dwords = first 64 KiB
  unsigned int v = a[idx];
  bool bad = ((v & 0xFFu) > 1u) || (((v >> 8) & 0xFFu) > 1u) ||
             (((v >> 16) & 0xFFu) > 1u) || ((v >> 24) > 1u);
  bool off = (v & 0xFFFFFF00u) != 0u;
  if (__any(bad) && (threadIdx.x & 63) == 0) atomicOr(&flags[0], 1);
  if (__any(off) && (threadIdx.x & 63) == 0) atomicOr(&flags[1], 1);
}

__global__ void normalize_adj(const unsigned char* __restrict__ a,
                              const int* __restrict__ flags,
                              unsigned char* __restrict__ out) {
  size_t i = (size_t)blockIdx.x * blockDim.x + threadIdx.x;
  int mode = flags[0] ? 2 : (flags[1] ? 1 : 0);
  unsigned char r;
  if (mode == 1)      r = (a[i] != 0);
  else if (mode == 0) r = (((const int*)a)[i] != 0);
  else                r = (((const float*)a)[i] != 0.f);
  out[i] = r;
}

// ---------------- X transpose ----------------
__global__ void transpose_x(const float* __restrict__ X, float* __restrict__ XT) {
  int g = blockIdx.x * blockDim.x + threadIdx.x;
  int k = g >> 6, b = g & 63;
  XT[g] = X[(size_t)b * KIN + k];
}

// ---------------- pack aligned in-block triangles ----------------
__global__ __launch_bounds__(256) void pack_wmid(const float* __restrict__ Wmid,
                                                 const unsigned char* __restrict__ adjN,
                                                 float* __restrict__ wpack) {
  int g = blockIdx.x * 256 + threadIdx.x;  // 65536 float4s
  int i = g >> 12;
  int rem = g & 4095;
  int j = rem >> 5;
  int q4 = (rem & 31) * 4;
  int n0 = 1 + i * TBLK;
  int size = NN - 1 - n0;
  if (size > TBLK) size = TBLK;
  float w[4];
#pragma unroll
  for (int e = 0; e < 4; ++e) {
    int q = q4 + e;
    float v = 0.f;
    if (q > j && j < size && q < size) {
      size_t idx = (size_t)(n0 + j) * NN + (size_t)(n0 + q);
      v = Wmid[idx] * (float)adjN[idx];
    }
    w[e] = v;
  }
  *(float4*)(wpack + (size_t)g * 4) = make_float4(w[0], w[1], w[2], w[3]);
}

// ---------------- unified partial GEMM ----------------
template <int MODE>
__global__ __launch_bounds__(256) void gemm_partial(
    const float* __restrict__ AT, const float* __restrict__ W,
    const unsigned char* __restrict__ adj, float* __restrict__ accT,
    int ldw, int col0, int ncols, int kPerChunk, int nColTiles)
{
  const int ct = blockIdx.x % nColTiles;
  const int kc = blockIdx.x / nColTiles;
  const int c0 = ct * 64;
  const int k0 = kc * kPerChunk;
  const int t = threadIdx.x;
  const int tb = t >> 4;
  const int tc = t & 15;

  __shared__ __align__(16) float At[16][64];
  __shared__ __align__(16) float Wt[16][64];

  float acc[4][4] = {};
  const int sk = t >> 4;
  const int sq = t & 15;

  for (int ks = k0; ks < k0 + kPerChunk; ks += 16) {
    const float4 av = *(const float4*)(AT + (size_t)(ks + sk) * 64 + sq * 4);
    *(float4*)(&At[sk][sq * 4]) = av;
    {
      const float* wrow = W + (size_t)(ks + sk) * ldw + col0;
      float w[4];
      float rowmask = 1.f;
      if (MODE == 2) rowmask = (float)adj[(size_t)(ks + sk) * NN + (NN - 1)];
#pragma unroll
      for (int e = 0; e < 4; ++e) {
        int cl = c0 + sq * 4 + e;
        float wv = 0.f;
        if (cl < ncols) {
          wv = wrow[cl];
          if (MODE == 1) wv *= (float)adj[(size_t)(ks + sk) * NN + col0 + cl];
          if (MODE == 2) wv *= rowmask;
        }
        w[e] = wv;
      }
      *(float4*)(&Wt[sk][sq * 4]) = make_float4(w[0], w[1], w[2], w[3]);
    }
    __syncthreads();
#pragma unroll
    for (int kk = 0; kk < 16; ++kk) {
      float a4[4], w4[4];
#pragma unroll
      for (int e = 0; e < 4; ++e) a4[e] = At[kk][tb * 4 + e];
#pragma unroll
      for (int e = 0; e < 4; ++e) w4[e] = Wt[kk][tc * 4 + e];
#pragma unroll
      for (int i = 0; i < 4; ++i)
#pragma unroll
        for (int j = 0; j < 4; ++j) acc[i][j] = fmaf(a4[i], w4[j], acc[i][j]);
    }
    __syncthreads();
  }

#pragma unroll
  for (int j = 0; j < 4; ++j) {
    int cl = c0 + tc * 4 + j;
    if (cl < ncols) {
      float* dst = accT + (size_t)(col0 + cl) * 64 + tb * 4;
#pragma unroll
      for (int i = 0; i < 4; ++i) atomicAdd(dst + i, acc[i][j]);
    }
  }
}

// ---------------- init finish ----------------
__global__ void init_finish(const float* __restrict__ out0accT, const float* __restrict__ b0,
                            const unsigned char* __restrict__ adjN, const int* __restrict__ nl_idx,
                            float* __restrict__ curT) {
  int g = blockIdx.x * blockDim.x + threadIdx.x;
  int n = g >> 6;
  float v = out0accT[g] + b0[n];
  v = apply_nl(nl_idx[0], v);
  curT[g] = adjN[n] ? v : 0.f;
}

// ---------------- fused solve v4: 16 self-applying solver WGs ----------------
// Solver bi: stage triangle + val/iv/id early; for each p<bi: prestage masked
// cross-weights (idle time), wait solveDone[p], apply rank-128 correction in
// registers; then sub-chunked 4-phase triangular solve; export; flag.
__global__ __launch_bounds__(256, 1) void fused_solve(
    const float* __restrict__ wpack, const float* __restrict__ Wmid,
    const unsigned char* __restrict__ adjN, const int* __restrict__ nlidx,
    const float* __restrict__ bmid, const float* __restrict__ Cbase,
    float* __restrict__ curT, float* __restrict__ deltaG, int* solveDone)
{
  __shared__ __align__(16) unsigned char smem[132096];
  float (*wmS)[TBLK]     = (float(*)[TBLK])(smem);           // 64 KiB triangle
  float (*wpr)[TBLK]     = (float(*)[TBLK])(smem + 65536);   // 64 KiB cross-pair weights
  float (*deltaFull)[64] = (float(*)[64])(smem + 65536);     // 32 KiB (aliases wpr post-apply)
  int* idS               = (int*)(smem + 131072);            // 512 B
  int* sfl               = (int*)(smem + 131584);

  const int bi = blockIdx.x;
  const int n0 = 1 + bi * TBLK;
  int size = NN - 1 - n0;
  if (size > TBLK) size = TBLK;
  const int tid = threadIdx.x;
  const int wv = tid >> 6;
  const int b = tid & 63;
  const int qbase = wv * 32;

  // ---- stage triangle (two halves to limit transient regs) ----
  {
    const float4* src = (const float4*)(wpack + (size_t)bi * TBLK * TBLK);
    float4 s0[8];
#pragma unroll
    for (int it = 0; it < 8; ++it) s0[it] = src[it * 256 + tid];
#pragma unroll
    for (int it = 0; it < 8; ++it) ((float4*)&wmS[0][0])[it * 256 + tid] = s0[it];
#pragma unroll
    for (int it = 0; it < 8; ++it) s0[it] = src[(8 + it) * 256 + tid];
#pragma unroll
    for (int it = 0; it < 8; ++it) ((float4*)&wmS[0][0])[(8 + it) * 256 + tid] = s0[it];
  }
  if (tid < TBLK) idS[tid] = (tid < size) ? nlidx[n0 + tid] : 3;

  // ---- val (Cbase + bias) and iv (init state) in registers ----
  float val[32], iv[32];
#pragma unroll
  for (int l = 0; l < 32; ++l) {
    int q = qbase + l, n = n0 + q;
    bool ok = q < size;
    val[l] = ok ? (Cbase[(size_t)n * 64 + b] + bmid[n]) : 0.f;
    iv[l] = ok ? curT[(size_t)n * 64 + b] : 0.f;
  }
  __syncthreads();

  // ---- incremental applies: val += delta_p @ W[rows_p, own cols] ----
#pragma unroll 1
  for (int p = 0; p < bi; ++p) {
    // prestage masked cross-weights (overlaps predecessors' solves)
    {
      const size_t rowg0 = (size_t)(1 + p * TBLK);
#pragma unroll 1
      for (int it = 0; it < 16; ++it) {
        int idx = it * 256 + tid;
        int r = idx >> 5, c4 = (idx & 31) * 4;
        const float* wrow = Wmid + (rowg0 + r) * NN + n0;
        const unsigned char* arow = adjN + (rowg0 + r) * NN + n0;
        float w[4];
#pragma unroll
        for (int e = 0; e < 4; ++e) {
          int cl = c4 + e;
          w[e] = (cl < size && arow[cl]) ? wrow[cl] : 0.f;
        }
        *(float4*)(&wpr[r][c4]) = make_float4(w[0], w[1], w[2], w[3]);
      }
    }
    // wait for producer p (bounded; barrier in loop also fences wpr staging)
    {
      int done = 0, cnt = 0;
      while (!done && cnt < 4000000) {
        if (tid == 0) *sfl = atomicAdd(&solveDone[p], 0);
        __syncthreads();
        done = *sfl;
        __syncthreads();
        ++cnt;
        if (!done) __builtin_amdgcn_s_sleep(2);
      }
    }
    __threadfence();  // acquire producer's deltaG
    // apply: 8 chunks of 16 k-steps
    const float* dsrc = deltaG + (size_t)p * TBLK * 64 + b;
#pragma unroll 1
    for (int kc = 0; kc < 8; ++kc) {
      float d[16];
#pragma unroll
      for (int k = 0; k < 16; ++k) d[k] = dsrc[(size_t)(kc * 16 + k) * 64];
#pragma unroll
      for (int k = 0; k < 16; ++k) {
        const float4* wr = (const float4*)(&wpr[kc * 16 + k][qbase]);
#pragma unroll
        for (int g2 = 0; g2 < 8; ++g2) {
          float4 w4 = wr[g2];
          val[g2 * 4 + 0] = fmaf(d[k], w4.x, val[g2 * 4 + 0]);
          val[g2 * 4 + 1] = fmaf(d[k], w4.y, val[g2 * 4 + 1]);
          val[g2 * 4 + 2] = fmaf(d[k], w4.z, val[g2 * 4 + 2]);
          val[g2 * 4 + 3] = fmaf(d[k], w4.w, val[g2 * 4 + 3]);
        }
      }
    }
    __syncthreads();  // before next p overwrites wpr
  }

  // ---- 4-phase chunked triangular solve; Phase A sub-chunked 8-wide ----
#pragma unroll 1
  for (int c = 0; c < 4; ++c) {
    if (wv == c) {
      const int jbase = c * 32;
      float cmx, cth, clk, csn, csp, csm;
      nl_cand(val[0], cmx, cth, clk, csn, csp, csm);
      int idv = idS[jbase];
#pragma unroll
      for (int s = 0; s < 4; ++s) {
        // preload in-sub 8x8 triangle rows into regs
        float4 tw[16];
#pragma unroll
        for (int m = 0; m < 8; ++m) {
          const float4* tr = (const float4*)(&wmS[jbase + s * 8 + m][qbase + s * 8]);
          tw[m * 2] = tr[0];
          tw[m * 2 + 1] = tr[1];
        }
        float ds[8];
        // ---- micro-solve: 8 serial steps, <=7 FMAs each ----
#pragma unroll
        for (int m = 0; m < 8; ++m) {
          const int jj = s * 8 + m;
          const int j = jbase + jj;
          float nv = nl_sel(idv, val[jj], cmx, cth, clk, csn, csp, csm);
          float delta = (j < size) ? (nv - iv[jj]) : 0.f;
          ds[m] = delta;
          deltaFull[j][b] = delta;
          if (jj < 31) idv = idS[jbase + jj + 1];
          if (m < 7) {
            val[s * 8 + m + 1] = fmaf(delta, TWEL(tw, m, m + 1), val[s * 8 + m + 1]);
            nl_cand(val[s * 8 + m + 1], cmx, cth, clk, csn, csp, csm);
#pragma unroll
            for (int l = m + 2; l < 8; ++l)
              val[s * 8 + l] = fmaf(delta, TWEL(tw, m, l), val[s * 8 + l]);
          }
        }
        // ---- batched rank-8 update of later subs (first group -> cand) ----
        if (s < 3) {
#pragma unroll
          for (int lg = (s + 1) * 2; lg < 8; ++lg) {
#pragma unroll
            for (int m = 0; m < 8; ++m) {
              const float4 w4 = *(const float4*)(&wmS[jbase + s * 8 + m][qbase + lg * 4]);
              val[lg * 4 + 0] = fmaf(ds[m], w4.x, val[lg * 4 + 0]);
              val[lg * 4 + 1] = fmaf(ds[m], w4.y, val[lg * 4 + 1]);
              val[lg * 4 + 2] = fmaf(ds[m], w4.z, val[lg * 4 + 2]);
              val[lg * 4 + 3] = fmaf(ds[m], w4.w, val[lg * 4 + 3]);
            }
            if (lg == (s + 1) * 2)
              nl_cand(val[(s + 1) * 8], cmx, cth, clk, csn, csp, csm);
          }
        }
      }
    }
    __syncthreads();  // deltas of chunk c visible
    if (wv > c) {
      // ---- Phase B: rank-32 update of own slots ----
#pragma unroll 1
      for (int jj = 0; jj < 32; ++jj) {
        const int j = c * 32 + jj;
        const float delta = deltaFull[j][b];
        const float4* wr = (const float4*)(&wmS[j][qbase]);
        float4 w0 = wr[0], w1 = wr[1], w2 = wr[2], w3 = wr[3];
        float4 w4 = wr[4], w5 = wr[5], w6 = wr[6], w7 = wr[7];
        val[0] = fmaf(delta, w0.x, val[0]);   val[1] = fmaf(delta, w0.y, val[1]);
        val[2] = fmaf(delta, w0.z, val[2]);   val[3] = fmaf(delta, w0.w, val[3]);
        val[4] = fmaf(delta, w1.x, val[4]);   val[5] = fmaf(delta, w1.y, val[5]);
        val[6] = fmaf(delta, w1.z, val[6]);   val[7] = fmaf(delta, w1.w, val[7]);
        val[8] = fmaf(delta, w2.x, val[8]);   val[9] = fmaf(delta, w2.y, val[9]);
        val[10] = fmaf(delta, w2.z, val[10]); val[11] = fmaf(delta, w2.w, val[11]);
        val[12] = fmaf(delta, w3.x, val[12]); val[13] = fmaf(delta, w3.y, val[13]);
        val[14] = fmaf(delta, w3.z, val[14]); val[15] = fmaf(delta, w3.w, val[15]);
        val[16] = fmaf(delta, w4.x, val[16]); val[17] = fmaf(delta, w4.y, val[17]);
        val[18] = fmaf(delta, w4.z, val[18]); val[19] = fmaf(delta, w4.w, val[19]);
        val[20] = fmaf(delta, w5.x, val[20]); val[21] = fmaf(delta, w5.y, val[21]);
        val[22] = fmaf(delta, w5.z, val[22]); val[23] = fmaf(delta, w5.w, val[23]);
        val[24] = fmaf(delta, w6.x, val[24]); val[25] = fmaf(delta, w6.y, val[25]);
        val[26] = fmaf(delta, w6.z, val[26]); val[27] = fmaf(delta, w6.w, val[27]);
        val[28] = fmaf(delta, w7.x, val[28]); val[29] = fmaf(delta, w7.y, val[29]);
        val[30] = fmaf(delta, w7.z, val[30]); val[31] = fmaf(delta, w7.w, val[31]);
      }
    }
    __syncthreads();
  }

  // ---- cooperative export: deltaG = deltas; curT += deltas (curT held iv) ----
  {
    const float4* sdel = (const float4*)&deltaFull[0][0];
    float4* dstD = (float4*)(deltaG + (size_t)bi * TBLK * 64);
    float4* dstC = (float4*)(curT + (size_t)n0 * 64);
#pragma unroll
    for (int it = 0; it < 8; ++it) {
      int v = it * 256 + tid;
      float4 d = sdel[v];
      dstD[v] = d;
      int r = v >> 4;
      if (r < size) {
        float4 cc = dstC[v];
        dstC[v] = make_float4(cc.x + d.x, cc.y + d.y, cc.z + d.z, cc.w + d.w);
      }
    }
  }
  __threadfence();
  __syncthreads();
  if (tid == 0) atomicExch(&solveDone[bi], 1);
}

// ---------------- final finish ----------------
__global__ void final_finish(const float* __restrict__ outaccT, const float* __restrict__ bout,
                             const int* __restrict__ nlidx, float* __restrict__ out) {
  int g = blockIdx.x * blockDim.x + threadIdx.x;
  int c = g >> 6, b = g & 63;
  float v = outaccT[g] + bout[c];
  v = apply_nl(nlidx[NN - 1], v);
  out[(size_t)b * DOUT + c] = v;
}

// ---------------- state transpose ----------------
__global__ __launch_bounds__(256) void transpose_state(const float* __restrict__ curT,
                                                       float* __restrict__ stateOut) {
  __shared__ float tile[64][65];
  int n0 = blockIdx.x * 64;
  for (int r = 0; r < 16; ++r) {
    int e = r * 256 + threadIdx.x;
    tile[e >> 6][e & 63] = curT[(size_t)(n0 + (e >> 6)) * 64 + (e & 63)];
  }
  __syncthreads();
  for (int r = 0; r < 16; ++r) {
    int e = r * 256 + threadIdx.x;
    int bb = e >> 6, nn2 = e & 63;
    stateOut[(size_t)bb * NN + n0 + nn2] = tile[nn2][bb];
  }
}

extern "C" void kernel_launch(void* const* d_in, const int* in_sizes, int n_in,
                              void* d_out, int out_size, void* d_ws, size_t ws_size,
                              hipStream_t stream) {
  const float* X = (const float*)d_in[0];
  const unsigned char* adj = (const unsigned char*)d_in[1];
  const int* nl_idx = (const int*)d_in[2];
  const float* W0 = (const float*)d_in[3];
  const float* b0 = (const float*)d_in[4];
  const float* W_mid = (const float*)d_in[5];
  const float* b_mid = (const float*)d_in[6];
  const float* W_out = (const float*)d_in[7];
  const float* b_out = (const float*)d_in[8];
  float* out = (float*)d_out;
  float* stateOut = out + BN * DOUT;

  char* ws = (char*)d_ws;
  unsigned char* adjN = (unsigned char*)(ws + 0);       // 4 MiB
  int* flags = (int*)(ws + 4194304);                    // 256 B
  float* XT = (float*)(ws + 4194560);                   // 256 KiB
  float* curT = (float*)(ws + 4456704);                 // 512 KiB
  float* Cbase = (float*)(ws + 4980992);                // 512 KiB (read-only after GEMM)
  float* out0accT = (float*)(ws + 5505280);             // 512 KiB
  float* outaccT = (float*)(ws + 6029568);              // 128 KiB
  float* wpack = (float*)(ws + 6160640);                // 1 MiB
  float* deltaG = (float*)(ws + 7209216);               // 512 KiB
  int* solveDone = flags + 8;

  hipMemsetAsync(flags, 0, 256, stream);
  hipMemsetAsync(Cbase, 0, 524288 + 524288 + 131072, stream);

  detect_adj<<<64, 256, 0, stream>>>((const unsigned int*)adj, flags);
  normalize_adj<<<16384, 256, 0, stream>>>(adj, flags, adjN);
  transpose_x<<<256, 256, 0, stream>>>(X, XT);
  pack_wmid<<<256, 256, 0, stream>>>(W_mid, adjN, wpack);

  gemm_partial<0><<<128, 256, 0, stream>>>(XT, W0, adjN, out0accT, NN, 0, NN, 256, 32);
  init_finish<<<512, 256, 0, stream>>>(out0accT, b0, adjN, nl_idx, curT);

  // Cbase: state_0 @ (W_mid * adj) for ALL columns (read-only afterwards)
  gemm_partial<1><<<256, 256, 0, stream>>>(curT, W_mid, adjN, Cbase, NN, 0, NN, 256, 32);

  // entire sequential middle: 16 self-applying solver WGs, one dispatch
  fused_solve<<<NBLK, 256, 0, stream>>>(wpack, W_mid, adjN, nl_idx, b_mid, Cbase,
                                        curT, deltaG, solveDone);

  gemm_partial<2><<<64, 256, 0, stream>>>(curT, W_out, adjN, outaccT, DOUT, 0, DOUT, 256, 8);
  final_finish<<<128, 256, 0, stream>>>(outaccT, b_out, nl_idx, out);
  transpose_state<<<32, 256, 0, stream>>>(curT, stateOut);
}

// Round 12
// 726.853 us; speedup vs baseline: 1.7478x; 1.1977x over previous
//
#include <hip/hip_runtime.h>
#include <math.h>

#define BN 64
#define KIN 1024
#define DOUT 512
#define NN 2048
#define TBLK 128
#define NBLK 16

__device__ __forceinline__ float softplus_f(float x) {
  float e = __expf(-fabsf(x));
  return fmaxf(x, 0.f) + __logf(1.f + e);
}
__device__ __forceinline__ float apply_nl(int id, float v) {
  switch (id) {
    case 0: return fmaxf(v, 0.f);
    case 1: { float e = __expf(2.f * v); return fmaf(-2.f, __builtin_amdgcn_rcpf(e + 1.f), 1.f); }
    case 2: return v >= 0.f ? v : 0.01f * v;
    case 3: return v;
    case 4: return __sinf(v);
    case 5: return softplus_f(v);
    default: return v - softplus_f(v);  // -softplus(-v)
  }
}

// Pipelined branchless nl: candidates computed early, select is a cndmask tree.
__device__ __forceinline__ void nl_cand(float v, float& mx, float& th, float& lk,
                                        float& sn, float& sp, float& sm) {
  mx = fmaxf(v, 0.f);
  lk = fmaf(fminf(v, 0.f), 0.01f, mx);
  float e = __expf(-fabsf(v));
  float e2 = e * e;
  float l1 = __logf(1.f + e);
  sp = mx + l1;
  sm = v - sp;
  th = __builtin_copysignf((1.f - e2) * __builtin_amdgcn_rcpf(1.f + e2), v);
  sn = __sinf(v);
}
__device__ __forceinline__ float nl_sel(int id, float v, float mx, float th, float lk,
                                        float sn, float sp, float sm) {
  float r = v;
  r = (id == 0) ? mx : r;
  r = (id == 1) ? th : r;
  r = (id == 2) ? lk : r;
  r = (id == 4) ? sn : r;
  r = (id == 5) ? sp : r;
  r = (id == 6) ? sm : r;
  return r;
}

// element (m-row, l-col) of per-sub triangle regs tw[16] (float4 pairs per row)
#define TWEL(tw, m, l) (((l) & 3) == 0 ? tw[(m)*2 + ((l) >> 2)].x : \
                        ((l) & 3) == 1 ? tw[(m)*2 + ((l) >> 2)].y : \
                        ((l) & 3) == 2 ? tw[(m)*2 + ((l) >> 2)].z : tw[(m)*2 + ((l) >> 2)].w)

// ---------------- adj dtype detection (parallel) ----------------
__global__ void detect_adj(const unsigned int* __restrict__ a, int* __restrict__ flags) {
  int idx = blockIdx.x * 256 + threadIdx.x;  // 16384 dwords = first 64 KiB
  unsigned int v = a[idx];
  bool bad = ((v & 0xFFu) > 1u) || (((v >> 8) & 0xFFu) > 1u) ||
             (((v >> 16) & 0xFFu) > 1u) || ((v >> 24) > 1u);
  bool off = (v & 0xFFFFFF00u) != 0u;
  if (__any(bad) && (threadIdx.x & 63) == 0) atomicOr(&flags[0], 1);
  if (__any(off) && (threadIdx.x & 63) == 0) atomicOr(&flags[1], 1);
}

__global__ void normalize_adj(const unsigned char* __restrict__ a,
                              const int* __restrict__ flags,
                              unsigned char* __restrict__ out) {
  size_t i = (size_t)blockIdx.x * blockDim.x + threadIdx.x;
  int mode = flags[0] ? 2 : (flags[1] ? 1 : 0);
  unsigned char r;
  if (mode == 1)      r = (a[i] != 0);
  else if (mode == 0) r = (((const int*)a)[i] != 0);
  else                r = (((const float*)a)[i] != 0.f);
  out[i] = r;
}

// ---------------- X transpose ----------------
__global__ void transpose_x(const float* __restrict__ X, float* __restrict__ XT) {
  int g = blockIdx.x * blockDim.x + threadIdx.x;
  int k = g >> 6, b = g & 63;
  XT[g] = X[(size_t)b * KIN + k];
}

// ---------------- pack aligned in-block triangles ----------------
__global__ __launch_bounds__(256) void pack_wmid(const float* __restrict__ Wmid,
                                                 const unsigned char* __restrict__ adjN,
                                                 float* __restrict__ wpack) {
  int g = blockIdx.x * 256 + threadIdx.x;  // 65536 float4s
  int i = g >> 12;
  int rem = g & 4095;
  int j = rem >> 5;
  int q4 = (rem & 31) * 4;
  int n0 = 1 + i * TBLK;
  int size = NN - 1 - n0;
  if (size > TBLK) size = TBLK;
  float w[4];
#pragma unroll
  for (int e = 0; e < 4; ++e) {
    int q = q4 + e;
    float v = 0.f;
    if (q > j && j < size && q < size) {
      size_t idx = (size_t)(n0 + j) * NN + (size_t)(n0 + q);
      v = Wmid[idx] * (float)adjN[idx];
    }
    w[e] = v;
  }
  *(float4*)(wpack + (size_t)g * 4) = make_float4(w[0], w[1], w[2], w[3]);
}

// ---------------- unified partial GEMM ----------------
template <int MODE>
__global__ __launch_bounds__(256) void gemm_partial(
    const float* __restrict__ AT, const float* __restrict__ W,
    const unsigned char* __restrict__ adj, float* __restrict__ accT,
    int ldw, int col0, int ncols, int kPerChunk, int nColTiles)
{
  const int ct = blockIdx.x % nColTiles;
  const int kc = blockIdx.x / nColTiles;
  const int c0 = ct * 64;
  const int k0 = kc * kPerChunk;
  const int t = threadIdx.x;
  const int tb = t >> 4;
  const int tc = t & 15;

  __shared__ __align__(16) float At[16][64];
  __shared__ __align__(16) float Wt[16][64];

  float acc[4][4] = {};
  const int sk = t >> 4;
  const int sq = t & 15;

  for (int ks = k0; ks < k0 + kPerChunk; ks += 16) {
    const float4 av = *(const float4*)(AT + (size_t)(ks + sk) * 64 + sq * 4);
    *(float4*)(&At[sk][sq * 4]) = av;
    {
      const float* wrow = W + (size_t)(ks + sk) * ldw + col0;
      float w[4];
      float rowmask = 1.f;
      if (MODE == 2) rowmask = (float)adj[(size_t)(ks + sk) * NN + (NN - 1)];
#pragma unroll
      for (int e = 0; e < 4; ++e) {
        int cl = c0 + sq * 4 + e;
        float wv = 0.f;
        if (cl < ncols) {
          wv = wrow[cl];
          if (MODE == 1) wv *= (float)adj[(size_t)(ks + sk) * NN + col0 + cl];
          if (MODE == 2) wv *= rowmask;
        }
        w[e] = wv;
      }
      *(float4*)(&Wt[sk][sq * 4]) = make_float4(w[0], w[1], w[2], w[3]);
    }
    __syncthreads();
#pragma unroll
    for (int kk = 0; kk < 16; ++kk) {
      float a4[4], w4[4];
#pragma unroll
      for (int e = 0; e < 4; ++e) a4[e] = At[kk][tb * 4 + e];
#pragma unroll
      for (int e = 0; e < 4; ++e) w4[e] = Wt[kk][tc * 4 + e];
#pragma unroll
      for (int i = 0; i < 4; ++i)
#pragma unroll
        for (int j = 0; j < 4; ++j) acc[i][j] = fmaf(a4[i], w4[j], acc[i][j]);
    }
    __syncthreads();
  }

#pragma unroll
  for (int j = 0; j < 4; ++j) {
    int cl = c0 + tc * 4 + j;
    if (cl < ncols) {
      float* dst = accT + (size_t)(col0 + cl) * 64 + tb * 4;
#pragma unroll
      for (int i = 0; i < 4; ++i) atomicAdd(dst + i, acc[i][j]);
    }
  }
}

// ---------------- init finish ----------------
__global__ void init_finish(const float* __restrict__ out0accT, const float* __restrict__ b0,
                            const unsigned char* __restrict__ adjN, const int* __restrict__ nl_idx,
                            float* __restrict__ curT) {
  int g = blockIdx.x * blockDim.x + threadIdx.x;
  int n = g >> 6;
  float v = out0accT[g] + b0[n];
  v = apply_nl(nl_idx[0], v);
  curT[g] = adjN[n] ? v : 0.f;
}

// ---------------- fused solve v5: per-chunk pipelined handoff ----------------
// Producer: after Phase A(c), wave c exports chunk-c deltas + flags chunkDone[bi*4+c]
// while waves >c run Phase B(c). Consumer: applies predecessor deltas chunk-by-chunk
// as flags arrive -> applies overlap the producer's remaining solve.
__global__ __launch_bounds__(256, 1) void fused_solve(
    const float* __restrict__ wpack, const float* __restrict__ Wmid,
    const unsigned char* __restrict__ adjN, const int* __restrict__ nlidx,
    const float* __restrict__ bmid, const float* __restrict__ Cbase,
    float* __restrict__ curT, float* __restrict__ deltaG, int* chunkDone)
{
  __shared__ __align__(16) unsigned char smem[132096];
  float (*wmS)[TBLK]     = (float(*)[TBLK])(smem);           // 64 KiB triangle
  float (*wpr)[TBLK]     = (float(*)[TBLK])(smem + 65536);   // 64 KiB cross-pair weights
  float (*deltaFull)[64] = (float(*)[64])(smem + 65536);     // 32 KiB (aliases wpr post-apply)
  int* idS               = (int*)(smem + 131072);            // 512 B
  int* sfl               = (int*)(smem + 131584);

  const int bi = blockIdx.x;
  const int n0 = 1 + bi * TBLK;
  int size = NN - 1 - n0;
  if (size > TBLK) size = TBLK;
  const int tid = threadIdx.x;
  const int wv = tid >> 6;
  const int b = tid & 63;
  const int qbase = wv * 32;

  // ---- stage triangle (two halves to limit transient regs) ----
  {
    const float4* src = (const float4*)(wpack + (size_t)bi * TBLK * TBLK);
    float4 s0[8];
#pragma unroll
    for (int it = 0; it < 8; ++it) s0[it] = src[it * 256 + tid];
#pragma unroll
    for (int it = 0; it < 8; ++it) ((float4*)&wmS[0][0])[it * 256 + tid] = s0[it];
#pragma unroll
    for (int it = 0; it < 8; ++it) s0[it] = src[(8 + it) * 256 + tid];
#pragma unroll
    for (int it = 0; it < 8; ++it) ((float4*)&wmS[0][0])[(8 + it) * 256 + tid] = s0[it];
  }
  if (tid < TBLK) idS[tid] = (tid < size) ? nlidx[n0 + tid] : 3;

  // ---- val (Cbase + bias) and iv (init state) in registers ----
  float val[32], iv[32];
#pragma unroll
  for (int l = 0; l < 32; ++l) {
    int q = qbase + l, n = n0 + q;
    bool ok = q < size;
    val[l] = ok ? (Cbase[(size_t)n * 64 + b] + bmid[n]) : 0.f;
    iv[l] = ok ? curT[(size_t)n * 64 + b] : 0.f;
  }
  __syncthreads();

  // ---- incremental applies, chunk-granular (overlap producer solves) ----
#pragma unroll 1
  for (int p = 0; p < bi; ++p) {
    // prestage masked cross-weights for pair (p -> bi)
    {
      const size_t rowg0 = (size_t)(1 + p * TBLK);
#pragma unroll 1
      for (int it = 0; it < 16; ++it) {
        int idx = it * 256 + tid;
        int r = idx >> 5, c4 = (idx & 31) * 4;
        const float* wrow = Wmid + (rowg0 + r) * NN + n0;
        const unsigned char* arow = adjN + (rowg0 + r) * NN + n0;
        float w[4];
#pragma unroll
        for (int e = 0; e < 4; ++e) {
          int cl = c4 + e;
          w[e] = (cl < size && arow[cl]) ? wrow[cl] : 0.f;
        }
        *(float4*)(&wpr[r][c4]) = make_float4(w[0], w[1], w[2], w[3]);
      }
    }
    __syncthreads();  // wpr staged

#pragma unroll 1
    for (int c2 = 0; c2 < 4; ++c2) {
      // wait for producer p's chunk c2
      {
        int done = 0, cnt = 0;
        while (!done && cnt < 4000000) {
          if (tid == 0) *sfl = atomicAdd(&chunkDone[p * 4 + c2], 0);
          __syncthreads();
          done = *sfl;
          __syncthreads();
          ++cnt;
          if (!done) __builtin_amdgcn_s_sleep(2);
        }
      }
      __threadfence();  // acquire producer's chunk deltas
      // apply rank-32: rows c2*32 .. c2*32+31 (full unroll; compiler pipelines)
      const float* dsrc = deltaG + ((size_t)p * TBLK + c2 * 32) * 64 + b;
#pragma unroll
      for (int r = 0; r < 32; ++r) {
        const float d = dsrc[(size_t)r * 64];
        const float4* wr = (const float4*)(&wpr[c2 * 32 + r][qbase]);
#pragma unroll
        for (int g2 = 0; g2 < 8; ++g2) {
          float4 w4 = wr[g2];
          val[g2 * 4 + 0] = fmaf(d, w4.x, val[g2 * 4 + 0]);
          val[g2 * 4 + 1] = fmaf(d, w4.y, val[g2 * 4 + 1]);
          val[g2 * 4 + 2] = fmaf(d, w4.z, val[g2 * 4 + 2]);
          val[g2 * 4 + 3] = fmaf(d, w4.w, val[g2 * 4 + 3]);
        }
      }
    }
    __syncthreads();  // before next p overwrites wpr
  }

  // ---- 4-phase chunked triangular solve; Phase A sub-chunked 8-wide ----
#pragma unroll 1
  for (int c = 0; c < 4; ++c) {
    if (wv == c) {
      const int jbase = c * 32;
      float cmx, cth, clk, csn, csp, csm;
      nl_cand(val[0], cmx, cth, clk, csn, csp, csm);
      int idv = idS[jbase];
#pragma unroll
      for (int s = 0; s < 4; ++s) {
        // preload in-sub 8x8 triangle rows into regs
        float4 tw[16];
#pragma unroll
        for (int m = 0; m < 8; ++m) {
          const float4* tr = (const float4*)(&wmS[jbase + s * 8 + m][qbase + s * 8]);
          tw[m * 2] = tr[0];
          tw[m * 2 + 1] = tr[1];
        }
        float ds[8];
        // ---- micro-solve: 8 serial steps ----
#pragma unroll
        for (int m = 0; m < 8; ++m) {
          const int jj = s * 8 + m;
          const int j = jbase + jj;
          float nv = nl_sel(idv, val[jj], cmx, cth, clk, csn, csp, csm);
          float delta = (j < size) ? (nv - iv[jj]) : 0.f;
          ds[m] = delta;
          deltaFull[j][b] = delta;
          if (jj < 31) idv = idS[jbase + jj + 1];
          if (m < 7) {
            val[s * 8 + m + 1] = fmaf(delta, TWEL(tw, m, m + 1), val[s * 8 + m + 1]);
            nl_cand(val[s * 8 + m + 1], cmx, cth, clk, csn, csp, csm);
#pragma unroll
            for (int l = m + 2; l < 8; ++l)
              val[s * 8 + l] = fmaf(delta, TWEL(tw, m, l), val[s * 8 + l]);
          }
        }
        // ---- batched rank-8 update of later subs (first group -> cand) ----
        if (s < 3) {
#pragma unroll
          for (int lg = (s + 1) * 2; lg < 8; ++lg) {
#pragma unroll
            for (int m = 0; m < 8; ++m) {
              const float4 w4 = *(const float4*)(&wmS[jbase + s * 8 + m][qbase + lg * 4]);
              val[lg * 4 + 0] = fmaf(ds[m], w4.x, val[lg * 4 + 0]);
              val[lg * 4 + 1] = fmaf(ds[m], w4.y, val[lg * 4 + 1]);
              val[lg * 4 + 2] = fmaf(ds[m], w4.z, val[lg * 4 + 2]);
              val[lg * 4 + 3] = fmaf(ds[m], w4.w, val[lg * 4 + 3]);
            }
            if (lg == (s + 1) * 2)
              nl_cand(val[(s + 1) * 8], cmx, cth, clk, csn, csp, csm);
          }
        }
      }
    }
    __syncthreads();  // deltas of chunk c visible in LDS
    if (wv == c) {
      // ---- wave c (idle in Phase B): export chunk deltas + flag ----
      const float4* sdel = (const float4*)(&deltaFull[c * 32][0]);  // 512 float4
      float4* dstD = (float4*)(deltaG + ((size_t)bi * TBLK + c * 32) * 64);
#pragma unroll
      for (int it = 0; it < 8; ++it) dstD[it * 64 + b] = sdel[it * 64 + b];
      __threadfence();  // wave-level vmcnt drain + release
      if (b == 0) atomicExch(&chunkDone[bi * 4 + c], 1);
    } else if (wv > c) {
      // ---- Phase B: rank-32 update of own slots (full unroll) ----
#pragma unroll
      for (int jj = 0; jj < 32; ++jj) {
        const int j = c * 32 + jj;
        const float delta = deltaFull[j][b];
        const float4* wr = (const float4*)(&wmS[j][qbase]);
#pragma unroll
        for (int g2 = 0; g2 < 8; ++g2) {
          float4 w4 = wr[g2];
          val[g2 * 4 + 0] = fmaf(delta, w4.x, val[g2 * 4 + 0]);
          val[g2 * 4 + 1] = fmaf(delta, w4.y, val[g2 * 4 + 1]);
          val[g2 * 4 + 2] = fmaf(delta, w4.z, val[g2 * 4 + 2]);
          val[g2 * 4 + 3] = fmaf(delta, w4.w, val[g2 * 4 + 3]);
        }
      }
    }
    __syncthreads();
  }

  // ---- final: curT += deltas (curT held iv) ----
  {
    const float4* sdel = (const float4*)&deltaFull[0][0];
    float4* dstC = (float4*)(curT + (size_t)n0 * 64);
#pragma unroll
    for (int it = 0; it < 8; ++it) {
      int v = it * 256 + tid;
      int r = v >> 4;
      if (r < size) {
        float4 d = sdel[v];
        float4 cc = dstC[v];
        dstC[v] = make_float4(cc.x + d.x, cc.y + d.y, cc.z + d.z, cc.w + d.w);
      }
    }
  }
}

// ---------------- final finish ----------------
__global__ void final_finish(const float* __restrict__ outaccT, const float* __restrict__ bout,
                             const int* __restrict__ nlidx, float* __restrict__ out) {
  int g = blockIdx.x * blockDim.x + threadIdx.x;
  int c = g >> 6, b = g & 63;
  float v = outaccT[g] + bout[c];
  v = apply_nl(nlidx[NN - 1], v);
  out[(size_t)b * DOUT + c] = v;
}

// ---------------- state transpose ----------------
__global__ __launch_bounds__(256) void transpose_state(const float* __restrict__ curT,
                                                       float* __restrict__ stateOut) {
  __shared__ float tile[64][65];
  int n0 = blockIdx.x * 64;
  for (int r = 0; r < 16; ++r) {
    int e = r * 256 + threadIdx.x;
    tile[e >> 6][e & 63] = curT[(size_t)(n0 + (e >> 6)) * 64 + (e & 63)];
  }
  __syncthreads();
  for (int r = 0; r < 16; ++r) {
    int e = r * 256 + threadIdx.x;
    int bb = e >> 6, nn2 = e & 63;
    stateOut[(size_t)bb * NN + n0 + nn2] = tile[nn2][bb];
  }
}

extern "C" void kernel_launch(void* const* d_in, const int* in_sizes, int n_in,
                              void* d_out, int out_size, void* d_ws, size_t ws_size,
                              hipStream_t stream) {
  const float* X = (const float*)d_in[0];
  const unsigned char* adj = (const unsigned char*)d_in[1];
  const int* nl_idx = (const int*)d_in[2];
  const float* W0 = (const float*)d_in[3];
  const float* b0 = (const float*)d_in[4];
  const float* W_mid = (const float*)d_in[5];
  const float* b_mid = (const float*)d_in[6];
  const float* W_out = (const float*)d_in[7];
  const float* b_out = (const float*)d_in[8];
  float* out = (float*)d_out;
  float* stateOut = out + BN * DOUT;

  char* ws = (char*)d_ws;
  unsigned char* adjN = (unsigned char*)(ws + 0);       // 4 MiB
  int* flags = (int*)(ws + 4194304);                    // 512 B: [0..1]=detect, [8..71]=chunkDone
  float* XT = (float*)(ws + 4194816);                   // 256 KiB
  float* curT = (float*)(ws + 4456960);                 // 512 KiB
  float* Cbase = (float*)(ws + 4981248);                // 512 KiB (read-only after GEMM)
  float* out0accT = (float*)(ws + 5505536);             // 512 KiB
  float* outaccT = (float*)(ws + 6029824);              // 128 KiB
  float* wpack = (float*)(ws + 6160896);                // 1 MiB
  float* deltaG = (float*)(ws + 7209472);               // 512 KiB -> end 7733760
  int* chunkDone = flags + 8;

  hipMemsetAsync(flags, 0, 512, stream);
  hipMemsetAsync(Cbase, 0, 524288 + 524288 + 131072, stream);

  detect_adj<<<64, 256, 0, stream>>>((const unsigned int*)adj, flags);
  normalize_adj<<<16384, 256, 0, stream>>>(adj, flags, adjN);
  transpose_x<<<256, 256, 0, stream>>>(X, XT);
  pack_wmid<<<256, 256, 0, stream>>>(W_mid, adjN, wpack);

  gemm_partial<0><<<128, 256, 0, stream>>>(XT, W0, adjN, out0accT, NN, 0, NN, 256, 32);
  init_finish<<<512, 256, 0, stream>>>(out0accT, b0, adjN, nl_idx, curT);

  // Cbase: state_0 @ (W_mid * adj) for ALL columns (read-only afterwards)
  gemm_partial<1><<<256, 256, 0, stream>>>(curT, W_mid, adjN, Cbase, NN, 0, NN, 256, 32);

  // entire sequential middle: 16 self-applying solver WGs, per-chunk pipelined
  fused_solve<<<NBLK, 256, 0, stream>>>(wpack, W_mid, adjN, nl_idx, b_mid, Cbase,
                                        curT, deltaG, chunkDone);

  gemm_partial<2><<<64, 256, 0, stream>>>(curT, W_out, adjN, outaccT, DOUT, 0, DOUT, 256, 8);
  final_finish<<<128, 256, 0, stream>>>(outaccT, b_out, nl_idx, out);
  transpose_state<<<32, 256, 0, stream>>>(curT, stateOut);
}